// Round 7
// baseline (375.014 us; speedup 1.0000x reference)
//
#include <hip/hip_runtime.h>

#define BATCH   4096
#define IN_DIM  1024
#define OUT_DIM 1024
#define NB      8                 // DEGREE + 1
#define NBK     7                 // basis funcs in the GEMM (d=1..7; d=0 is a bias)
#define KD2     (IN_DIM * NBK)    // 7168
// Workspace K-layout (d-major): k = (d-1)*IN_DIM + i, for BOTH A and Bt.
// R5 lesson: hipLaunchCooperativeKernel is NOT graph-capturable here (hang x2).
// R6 lesson: split-K atomicAdd epilogue was the gemm bottleneck (94->66 us
// when replaced by plain stores + reduce). This round: fold the reduce into
// the gemm via a last-block-finishes per-tile flag (same XCD, L2-hot).

typedef __bf16 bf16x8 __attribute__((ext_vector_type(8)));
typedef float  f32x4  __attribute__((ext_vector_type(4)));
typedef unsigned short us8 __attribute__((ext_vector_type(8)));
typedef unsigned short us4 __attribute__((ext_vector_type(4)));

__device__ __forceinline__ unsigned short f2bf(float f) {
    unsigned int u = __float_as_uint(f);
    u += 0x7fffu + ((u >> 16) & 1u);   // round-to-nearest-even
    return (unsigned short)(u >> 16);
}

// fast tanh: 1 - 2/(e^{2x}+1) via v_exp_f32 + v_rcp_f32; exact limits at +-inf.
__device__ __forceinline__ float fast_tanh(float x) {
    const float LOG2E_X2 = 2.8853900817779268f;   // 2*log2(e)
    float e = __builtin_amdgcn_exp2f(x * LOG2E_X2);
    return 1.0f - 2.0f * __builtin_amdgcn_rcpf(e + 1.0f);
}

__device__ __forceinline__ void ld_lds16(const unsigned short* g, unsigned short* l) {
    __builtin_amdgcn_global_load_lds(
        (const __attribute__((address_space(1))) void*)g,
        (__attribute__((address_space(3))) void*)l, 16, 0, 0);
}

// ---------------------------------------------------------------------------
// Kernel 1a: basis prep — R4 body + per-iteration flag zeroing (block 0).
// 2048 blocks (8/CU). Thread owns 8 contiguous i of one row; float4 loads up
// front; 7x us8 16B stores per d-plane. A[b][(d-1)*1024+i] = bf16(P_d(tanh x)).
// ---------------------------------------------------------------------------
#define BASIS_BLOCKS (BATCH / 2)               // 2048

__global__ __launch_bounds__(256) void basis_kernel(
    const float* __restrict__ x, const float* __restrict__ ap,
    const float* __restrict__ qp, unsigned short* __restrict__ Aw,
    unsigned int* flags) {                     // 256 tile counters (or null)
    const int tid = threadIdx.x;
    if (flags && blockIdx.x == 0) flags[tid] = 0u;   // re-arm per iteration
    const float a = ap[0], q = qp[0];
    const int b  = blockIdx.x * 2 + (tid >> 7);
    const int i0 = (tid & 127) * 8;

    const float* xs = x + (size_t)b * IN_DIM + i0;
    float4 v0 = *(const float4*)xs;          // both loads issued before any use
    float4 v1 = *(const float4*)(xs + 4);

    float xe[8] = {v0.x, v0.y, v0.z, v0.w, v1.x, v1.y, v1.z, v1.w};
    float pm2[8], pm1[8];
    us8 ov;
#pragma unroll
    for (int e = 0; e < 8; ++e) {
        xe[e] = fast_tanh(xe[e]);
        pm2[e] = 1.0f;
        pm1[e] = xe[e] - a;
        ov[e] = f2bf(pm1[e]);
    }
    unsigned short* arow = Aw + (size_t)b * KD2 + i0;
    *(us8*)arow = ov;                         // d=1 plane
    float qn = q, qn1 = 1.0f;
#pragma unroll
    for (int n = 2; n < NB; ++n) {
        qn *= q; qn1 *= q;
#pragma unroll
        for (int e = 0; e < 8; ++e) {
            float pn = (xe[e] - (a + qn)) * pm1[e] - a * qn1 * pm2[e];
            pm2[e] = pm1[e]; pm1[e] = pn;
            ov[e] = f2bf(pn);
        }
        *(us8*)(arow + (size_t)(n - 1) * IN_DIM) = ov;   // d=n plane, 16 B
    }
}

// ---------------------------------------------------------------------------
// Kernel 1b: coeffs repack (d-major) + exact fp32 bias partials. UNCHANGED.
// ---------------------------------------------------------------------------
#define REPACK_BLOCKS 512
#define TI 32
#define TO 64
#define RSTR 232    // LDS row stride (ushorts) per o: 224 data + 8 pad

__global__ __launch_bounds__(256) void repack_kernel(
    const float* __restrict__ coeffs,
    unsigned short* __restrict__ Bt,
    float* __restrict__ bias_part) {  // [32][OUT_DIM]
    __shared__ __align__(16) unsigned short lt[TO * RSTR + 512];  // 30.0 KB
    const int tid = threadIdx.x;
    const int bid = blockIdx.x;
    const int g  = bid & 31;
    const int i0 = g * TI;
    const int o0 = (bid >> 5) * TO;
    const int o_local = tid & 63;
    float bpart = 0.f;
#pragma unroll
    for (int pass = 0; pass < 8; ++pass) {
        const int i_local = pass * 4 + (tid >> 6);
        const float* src = coeffs +
            ((size_t)(i0 + i_local) * OUT_DIM + (o0 + o_local)) * NB;
        float4 v0 = *(const float4*)src;
        float4 v1 = *(const float4*)(src + 4);
        bpart += v0.x;                       // d = 0 -> exact fp32 bias
        unsigned short* dst = lt + o_local * RSTR + i_local;
        dst[0]   = f2bf(v0.y); dst[32]  = f2bf(v0.z); dst[64]  = f2bf(v0.w);
        dst[96]  = f2bf(v1.x); dst[128] = f2bf(v1.y); dst[160] = f2bf(v1.z);
        dst[192] = f2bf(v1.w);
    }
    float* sb = (float*)(lt + TO * RSTR);    // 256 floats
    sb[(tid >> 6) * 64 + o_local] = bpart;
    __syncthreads();
    if (tid < 64)
        bias_part[(size_t)g * OUT_DIM + o0 + tid] =
            sb[tid] + sb[64 + tid] + sb[128 + tid] + sb[192 + tid];
#pragma unroll
    for (int p = 0; p < 7; ++p) {
        const int o = tid >> 2;
        const int c = tid & 3;
        us8 v = *(const us8*)(lt + o * RSTR + p * 32 + c * 8);
        *(us8*)(Bt + (size_t)(o0 + o) * KD2 + (size_t)p * IN_DIM + i0 + c * 8) = v;
    }
}

// ---------------------------------------------------------------------------
// Kernel 1c: zero C — used ONLY by the atomic fallback path.
// ---------------------------------------------------------------------------
#define ZERO_BLOCKS   (BATCH * OUT_DIM / 4096) // 1024

__global__ __launch_bounds__(256) void zero_kernel(float* __restrict__ C) {
    float* dst = C + (size_t)blockIdx.x * 4096 + threadIdx.x * 4;
    const f32x4 zero = {0.f, 0.f, 0.f, 0.f};
#pragma unroll
    for (int j = 0; j < 4; ++j) *(f32x4*)(dst + j * 1024) = zero;
}

// ---------------------------------------------------------------------------
// Shared GEMM geometry (proven 128x128 body). Variadic macro so epilogue
// commas are safe.
// ---------------------------------------------------------------------------
#define BM 128
#define BN 128
#define BK 64
#define KSPLIT 4
#define KCH (KD2 / KSPLIT)   // 1792 -> 28 iters of BK=64

#define GEMM_BODY(...)                                                         \
    __shared__ __align__(16) unsigned short lA[BM * BK];  /* 16 KB */          \
    __shared__ __align__(16) unsigned short lB[BN * BK];  /* 16 KB */          \
    const int tid  = threadIdx.x;                                              \
    const int bidx = blockIdx.x;                                               \
    const int m0 = (((bidx >> 3) & 3) * 8 + (bidx & 7)) * BM;                  \
    const int n0 = ((bidx >> 5) & 7) * BN;                                     \
    const int ch = bidx >> 8;                                                  \
    const size_t kb = (size_t)ch * KCH;                                        \
    const int lane  = tid & 63;                                                \
    const int wid   = tid >> 6;                                                \
    const int wm    = (wid & 1) * 64;                                          \
    const int wn    = (wid >> 1) * 64;                                         \
    const int row16 = lane & 15;                                               \
    const int quad  = lane >> 4;                                               \
    int aOff[4], bOff[4];                                                      \
    _Pragma("unroll") for (int mt = 0; mt < 4; ++mt) {                         \
        int r = wm + mt * 16 + row16;                                          \
        aOff[mt] = r * BK + ((quad ^ (r & 7)) * 8);                            \
    }                                                                          \
    _Pragma("unroll") for (int nt = 0; nt < 4; ++nt) {                         \
        int c = wn + nt * 16 + row16;                                          \
        bOff[nt] = c * BK + ((quad ^ (c & 7)) * 8);                            \
    }                                                                          \
    const int r0 = tid >> 3, s0 = tid & 7;                                     \
    const unsigned short* gA0 = A  + (size_t)(m0 + r0) * KD2 + kb              \
                                + ((s0 ^ (r0 & 7)) * 8);                       \
    const unsigned short* gB0 = Bt + (size_t)(n0 + r0) * KD2 + kb              \
                                + ((s0 ^ (r0 & 7)) * 8);                       \
    unsigned short* dA = lA + tid * 8;                                         \
    unsigned short* dB = lB + tid * 8;                                         \
    f32x4 acc[4][4] = {};                                                      \
    for (int k0 = 0; k0 < KCH; k0 += BK) {                                     \
        _Pragma("unroll") for (int j = 0; j < 4; ++j)                          \
            ld_lds16(gA0 + k0 + (size_t)j * 32 * KD2, dA + j * 2048);          \
        _Pragma("unroll") for (int j = 0; j < 4; ++j)                          \
            ld_lds16(gB0 + k0 + (size_t)j * 32 * KD2, dB + j * 2048);          \
        __syncthreads();                                                       \
        _Pragma("unroll") for (int kk = 0; kk < 2; ++kk) {                     \
            const int xo = kk * 32;                                            \
            bf16x8 aF[4], bF[4];                                               \
            _Pragma("unroll") for (int mt = 0; mt < 4; ++mt)                   \
                aF[mt] = *(const bf16x8*)(lA + (aOff[mt] ^ xo));               \
            _Pragma("unroll") for (int nt = 0; nt < 4; ++nt)                   \
                bF[nt] = *(const bf16x8*)(lB + (bOff[nt] ^ xo));               \
            _Pragma("unroll") for (int mt = 0; mt < 4; ++mt)                   \
                _Pragma("unroll") for (int nt = 0; nt < 4; ++nt)               \
                    acc[mt][nt] = __builtin_amdgcn_mfma_f32_16x16x32_bf16(     \
                        aF[mt], bF[nt], acc[mt][nt], 0, 0, 0);                 \
        }                                                                      \
        __syncthreads();                                                       \
    }                                                                          \
    if (ch == 0) {                                                             \
        float* sbw = (float*)lA;   /* safe: loop ended with __syncthreads */   \
        if (tid < BN) {                                                        \
            float s = 0.f;                                                     \
            _Pragma("unroll") for (int g = 0; g < 32; ++g)                     \
                s += bias_part[(size_t)g * OUT_DIM + n0 + tid];                \
            sbw[tid] = s;                                                      \
        }                                                                      \
        __syncthreads();                                                       \
    }                                                                          \
    const float* sb = (const float*)lA;                                        \
    __VA_ARGS__

// Plain-store split-K with in-kernel flag reduction:
//  ch==0 -> C (acc+bias); ch=1..3 -> Cp planes. Each block: stores,
//  __threadfence, __syncthreads, tid0 atomicAdd(tile counter). The block
//  seeing old==3 (all four done; same XCD by construction, so partials are
//  L2-hot) sums C + p1 + p2 + p3 (same order as the old reduce_kernel ->
//  bit-identical) via volatile (coherent) loads and rewrites C.
__global__ __launch_bounds__(256, 4) void gemm_store(
    const unsigned short* __restrict__ A,    // bf16 bits [BATCH][KD2]
    const unsigned short* __restrict__ Bt,   // bf16 bits [OUT_DIM][KD2]
    const float* __restrict__ bias_part,     // [32][OUT_DIM]
    float* __restrict__ Cp,                  // [3][BATCH*OUT_DIM] partials
    unsigned int* flags,                     // [256] per-tile counters (zeroed)
    float* __restrict__ C) {                 // [BATCH][OUT_DIM]
    GEMM_BODY(
        float* dst = (ch == 0) ? C : (Cp + (size_t)(ch - 1) * BATCH * OUT_DIM);
        _Pragma("unroll") for (int mt = 0; mt < 4; ++mt) {
            const int rbase = m0 + wm + mt * 16 + quad * 4;
            _Pragma("unroll") for (int nt = 0; nt < 4; ++nt) {
                const int col = n0 + wn + nt * 16 + row16;
                const float bv = (ch == 0) ? sb[wn + nt * 16 + row16] : 0.f;
                _Pragma("unroll") for (int r = 0; r < 4; ++r)
                    dst[(size_t)(rbase + r) * OUT_DIM + col] =
                        acc[mt][nt][r] + bv;
            }
        }
        __threadfence();                 /* release: my stores visible */
        __syncthreads();                 /* whole block done fencing */
        __shared__ int s_last;
        if (tid == 0)
            s_last = (atomicAdd(&flags[bidx & 255], 1u) == 3u) ? 1 : 0;
        __syncthreads();
        if (s_last) {
            __threadfence();             /* acquire before reading partials */
            const size_t P = (size_t)BATCH * OUT_DIM;
            const int rr = tid >> 5;             /* 0..7 */
            const int cc = (tid & 31) * 4;       /* 0..124 */
            _Pragma("unroll 1") for (int p = 0; p < 16; ++p) {
                const size_t idx =
                    (size_t)(m0 + p * 8 + rr) * OUT_DIM + n0 + cc;
                f32x4 v  = *(volatile const f32x4*)(C + idx);
                f32x4 v1 = *(volatile const f32x4*)(Cp + idx);
                f32x4 v2 = *(volatile const f32x4*)(Cp + P + idx);
                f32x4 v3 = *(volatile const f32x4*)(Cp + 2 * P + idx);
                f32x4 s = v + v1 + v2 + v3;
                *(f32x4*)(C + idx) = s;
            }
        }
    )
}

// Atomic variant (fallback path, identical to R3/R4 gemm_kernel).
__global__ __launch_bounds__(256, 4) void gemm_atomic(
    const unsigned short* __restrict__ A,
    const unsigned short* __restrict__ Bt,
    const float* __restrict__ bias_part,
    float* __restrict__ C) {                 // pre-zeroed
    GEMM_BODY(
        _Pragma("unroll") for (int mt = 0; mt < 4; ++mt) {
            const int rbase = m0 + wm + mt * 16 + quad * 4;
            _Pragma("unroll") for (int nt = 0; nt < 4; ++nt) {
                const int col = n0 + wn + nt * 16 + row16;
                const float bv = (ch == 0) ? sb[wn + nt * 16 + row16] : 0.f;
                _Pragma("unroll") for (int r = 0; r < 4; ++r)
                    atomicAdd(&C[(size_t)(rbase + r) * OUT_DIM + col],
                              acc[mt][nt][r] + bv);
            }
        }
    )
}

// ---------------------------------------------------------------------------
// Fallback (only if ws too small): fp32, block per batch row, basis in LDS.
// ---------------------------------------------------------------------------
__global__ __launch_bounds__(256) void fallback_kernel(
    const float* __restrict__ x, const float* __restrict__ ap,
    const float* __restrict__ qp, const float* __restrict__ coeffs,
    float* __restrict__ out) {
    __shared__ float sb[IN_DIM][NB];   // 32 KB
    const int b = blockIdx.x;
    const float a = ap[0], q = qp[0];
    for (int i = threadIdx.x; i < IN_DIM; i += 256) {
        float xt = fast_tanh(x[(size_t)b * IN_DIM + i]);
        float p0 = 1.0f, p1 = xt - a;
        sb[i][0] = p0; sb[i][1] = p1;
        float qn = q, qn1 = 1.0f;
#pragma unroll
        for (int n = 2; n < NB; ++n) {
            qn *= q; qn1 *= q;
            float p2 = (xt - (a + qn)) * p1 - a * qn1 * p0;
            sb[i][n] = p2;
            p0 = p1; p1 = p2;
        }
    }
    __syncthreads();
    float acc[4] = {0.f, 0.f, 0.f, 0.f};
    for (int i = 0; i < IN_DIM; ++i) {
        float bb[NB];
#pragma unroll
        for (int d = 0; d < NB; ++d) bb[d] = sb[i][d];
#pragma unroll
        for (int j = 0; j < 4; ++j) {
            int o = threadIdx.x + j * 256;
            const float* cf = coeffs + ((size_t)i * OUT_DIM + o) * NB;
            float s = 0.f;
#pragma unroll
            for (int d = 0; d < NB; ++d) s += bb[d] * cf[d];
            acc[j] += s;
        }
    }
#pragma unroll
    for (int j = 0; j < 4; ++j)
        out[(size_t)b * OUT_DIM + threadIdx.x + j * 256] = acc[j];
}

// ---------------------------------------------------------------------------
extern "C" void kernel_launch(void* const* d_in, const int* in_sizes, int n_in,
                              void* d_out, int out_size, void* d_ws, size_t ws_size,
                              hipStream_t stream) {
    const float* x      = (const float*)d_in[0];
    const float* a      = (const float*)d_in[1];
    const float* q      = (const float*)d_in[2];
    const float* coeffs = (const float*)d_in[3];
    float* out = (float*)d_out;

    const size_t needA = (size_t)BATCH * KD2 * sizeof(unsigned short);   // 56 MB
    const size_t needB = (size_t)OUT_DIM * KD2 * sizeof(unsigned short); // 14 MB
    const size_t needBias = 32 * (size_t)OUT_DIM * sizeof(float);        // 128 KB
    const size_t needFlags = 256 * sizeof(unsigned int);                 // 1 KB
    const size_t needCp = 3 * (size_t)BATCH * OUT_DIM * sizeof(float);   // 48 MB

    if (ws_size >= needA + needB + needBias + needFlags + needCp) {
        // Preferred path: plain-store split-K + in-kernel flag reduce.
        unsigned short* Aw = (unsigned short*)d_ws;
        unsigned short* Bt = Aw + (size_t)BATCH * KD2;
        float* bias_part = (float*)((char*)d_ws + needA + needB);
        unsigned int* flags = (unsigned int*)((char*)d_ws + needA + needB + needBias);
        float* Cp = (float*)((char*)d_ws + needA + needB + needBias + needFlags);
        basis_kernel<<<BASIS_BLOCKS, 256, 0, stream>>>(x, a, q, Aw, flags);
        repack_kernel<<<REPACK_BLOCKS, 256, 0, stream>>>(coeffs, Bt, bias_part);
        gemm_store<<<(BATCH / BM) * (OUT_DIM / BN) * KSPLIT, 256, 0, stream>>>(
            Aw, Bt, bias_part, Cp, flags, out);
    } else if (ws_size >= needA + needB + needBias) {
        // Atomic path (R4-identical, known-good 202 us).
        unsigned short* Aw = (unsigned short*)d_ws;
        unsigned short* Bt = Aw + (size_t)BATCH * KD2;
        float* bias_part = (float*)((char*)d_ws + needA + needB);
        basis_kernel<<<BASIS_BLOCKS, 256, 0, stream>>>(x, a, q, Aw, nullptr);
        repack_kernel<<<REPACK_BLOCKS, 256, 0, stream>>>(coeffs, Bt, bias_part);
        zero_kernel<<<ZERO_BLOCKS, 256, 0, stream>>>(out);
        gemm_atomic<<<(BATCH / BM) * (OUT_DIM / BN) * KSPLIT, 256, 0, stream>>>(
            Aw, Bt, bias_part, out);
    } else {
        fallback_kernel<<<BATCH, 256, 0, stream>>>(x, a, q, coeffs, out);
    }
}

// Round 8
// 176.732 us; speedup vs baseline: 2.1219x; 2.1219x over previous
//
#include <hip/hip_runtime.h>

#define BATCH   4096
#define IN_DIM  1024
#define OUT_DIM 1024
#define NB      8                 // DEGREE + 1
#define NBK     7                 // basis funcs in the GEMM (d=1..7; d=0 is a bias)
#define KD2     (IN_DIM * NBK)    // 7168
// Workspace K-layout (d-major): k = (d-1)*IN_DIM + i, for BOTH A and Bt.
// R5 lesson: hipLaunchCooperativeKernel is NOT graph-capturable here (hang x2).
// R7 lesson: device-scope __threadfence in a hot kernel forces L2
// writeback/invalidate on non-coherent-XCD hardware -> FETCH +46 MB,
// MfmaUtil 38->9%, 4x slowdown. Cross-workgroup dataflow stays in separate
// dispatches (R6 structure, 180 us). This round: R6 minus one dispatch
// (basis+repack fused into prep_kernel).

typedef __bf16 bf16x8 __attribute__((ext_vector_type(8)));
typedef float  f32x4  __attribute__((ext_vector_type(4)));
typedef unsigned short us8 __attribute__((ext_vector_type(8)));
typedef unsigned short us4 __attribute__((ext_vector_type(4)));

__device__ __forceinline__ unsigned short f2bf(float f) {
    unsigned int u = __float_as_uint(f);
    u += 0x7fffu + ((u >> 16) & 1u);   // round-to-nearest-even
    return (unsigned short)(u >> 16);
}

// fast tanh: 1 - 2/(e^{2x}+1) via v_exp_f32 + v_rcp_f32; exact limits at +-inf.
__device__ __forceinline__ float fast_tanh(float x) {
    const float LOG2E_X2 = 2.8853900817779268f;   // 2*log2(e)
    float e = __builtin_amdgcn_exp2f(x * LOG2E_X2);
    return 1.0f - 2.0f * __builtin_amdgcn_rcpf(e + 1.0f);
}

__device__ __forceinline__ void ld_lds16(const unsigned short* g, unsigned short* l) {
    __builtin_amdgcn_global_load_lds(
        (const __attribute__((address_space(1))) void*)g,
        (__attribute__((address_space(3))) void*)l, 16, 0, 0);
}

// ---------------------------------------------------------------------------
// Kernel 1: fused prep (basis + repack), two block-role ranges.
//  [0, 512):      coeffs repack patch (heavier; scheduled first) + fp32 bias
//  [512, 2560):   basis rows, 2 rows/block (R4/R6 body: float4 loads up
//                 front, fp32 recurrence, 7x us8 16B stores per d-plane)
// LDS 30 KB (repack only) -> 5 blocks/CU; basis blocks don't touch it.
// ---------------------------------------------------------------------------
#define REPACK_BLOCKS 512
#define BASIS_BLOCKS  (BATCH / 2)              // 2048
#define PREP_BLOCKS   (REPACK_BLOCKS + BASIS_BLOCKS)
#define TI 32
#define TO 64
#define RSTR 232    // LDS row stride (ushorts) per o: 224 data + 8 pad

__global__ __launch_bounds__(256) void prep_kernel(
    const float* __restrict__ x, const float* __restrict__ ap,
    const float* __restrict__ qp, const float* __restrict__ coeffs,
    unsigned short* __restrict__ Aw, unsigned short* __restrict__ Bt,
    float* __restrict__ bias_part) {  // [32][OUT_DIM]
    __shared__ __align__(16) unsigned short lt[TO * RSTR + 512];  // 30.0 KB
    const int tid = threadIdx.x;

    if (blockIdx.x < REPACK_BLOCKS) {
        // ---- repack + bias partials: patch i0..i0+32 x o0..o0+64 ----
        const int bid = blockIdx.x;
        const int g  = bid & 31;
        const int i0 = g * TI;
        const int o0 = (bid >> 5) * TO;
        const int o_local = tid & 63;
        float bpart = 0.f;
#pragma unroll
        for (int pass = 0; pass < 8; ++pass) {
            const int i_local = pass * 4 + (tid >> 6);
            const float* src = coeffs +
                ((size_t)(i0 + i_local) * OUT_DIM + (o0 + o_local)) * NB;
            float4 v0 = *(const float4*)src;
            float4 v1 = *(const float4*)(src + 4);
            bpart += v0.x;                       // d = 0 -> exact fp32 bias
            // LDS stage, d-major per o: lt[o][d-1][i_local] (stride 32 per d)
            unsigned short* dst = lt + o_local * RSTR + i_local;
            dst[0]   = f2bf(v0.y); dst[32]  = f2bf(v0.z); dst[64]  = f2bf(v0.w);
            dst[96]  = f2bf(v1.x); dst[128] = f2bf(v1.y); dst[160] = f2bf(v1.z);
            dst[192] = f2bf(v1.w);
        }
        float* sb = (float*)(lt + TO * RSTR);    // 256 floats
        sb[(tid >> 6) * 64 + o_local] = bpart;
        __syncthreads();
        if (tid < 64)
            bias_part[(size_t)g * OUT_DIM + o0 + tid] =
                sb[tid] + sb[64 + tid] + sb[128 + tid] + sb[192 + tid];
        // write phase: thread -> (o = tid>>2, c = tid&3); 7 d-groups of 64B
#pragma unroll
        for (int p = 0; p < 7; ++p) {
            const int o = tid >> 2;
            const int c = tid & 3;
            us8 v = *(const us8*)(lt + o * RSTR + p * 32 + c * 8);
            *(us8*)(Bt + (size_t)(o0 + o) * KD2 + (size_t)p * IN_DIM + i0 + c * 8) = v;
        }
        return;
    }

    // ---- basis: 2 rows/block; thread owns 8 contiguous i of one row ----
    const int bb  = blockIdx.x - REPACK_BLOCKS;
    const float a = ap[0], q = qp[0];
    const int b  = bb * 2 + (tid >> 7);
    const int i0 = (tid & 127) * 8;

    const float* xs = x + (size_t)b * IN_DIM + i0;
    float4 v0 = *(const float4*)xs;          // both loads issued before any use
    float4 v1 = *(const float4*)(xs + 4);

    float xe[8] = {v0.x, v0.y, v0.z, v0.w, v1.x, v1.y, v1.z, v1.w};
    float pm2[8], pm1[8];
    us8 ov;
#pragma unroll
    for (int e = 0; e < 8; ++e) {
        xe[e] = fast_tanh(xe[e]);
        pm2[e] = 1.0f;
        pm1[e] = xe[e] - a;
        ov[e] = f2bf(pm1[e]);
    }
    unsigned short* arow = Aw + (size_t)b * KD2 + i0;
    *(us8*)arow = ov;                         // d=1 plane
    float qn = q, qn1 = 1.0f;
#pragma unroll
    for (int n = 2; n < NB; ++n) {
        qn *= q; qn1 *= q;
#pragma unroll
        for (int e = 0; e < 8; ++e) {
            float pn = (xe[e] - (a + qn)) * pm1[e] - a * qn1 * pm2[e];
            pm2[e] = pm1[e]; pm1[e] = pn;
            ov[e] = f2bf(pn);
        }
        *(us8*)(arow + (size_t)(n - 1) * IN_DIM) = ov;   // d=n plane, 16 B
    }
}

// ---------------------------------------------------------------------------
// zero C — used ONLY by the atomic fallback path.
// ---------------------------------------------------------------------------
#define ZERO_BLOCKS   (BATCH * OUT_DIM / 4096) // 1024

__global__ __launch_bounds__(256) void zero_kernel(float* __restrict__ C) {
    float* dst = C + (size_t)blockIdx.x * 4096 + threadIdx.x * 4;
    const f32x4 zero = {0.f, 0.f, 0.f, 0.f};
#pragma unroll
    for (int j = 0; j < 4; ++j) *(f32x4*)(dst + j * 1024) = zero;
}

// ---------------------------------------------------------------------------
// Shared GEMM geometry (proven 128x128 body). Variadic macro so epilogue
// commas are safe.
// ---------------------------------------------------------------------------
#define BM 128
#define BN 128
#define BK 64
#define KSPLIT 4
#define KCH (KD2 / KSPLIT)   // 1792 -> 28 iters of BK=64

#define GEMM_BODY(...)                                                         \
    __shared__ __align__(16) unsigned short lA[BM * BK];  /* 16 KB */          \
    __shared__ __align__(16) unsigned short lB[BN * BK];  /* 16 KB */          \
    const int tid  = threadIdx.x;                                              \
    const int bidx = blockIdx.x;                                               \
    const int m0 = (((bidx >> 3) & 3) * 8 + (bidx & 7)) * BM;                  \
    const int n0 = ((bidx >> 5) & 7) * BN;                                     \
    const int ch = bidx >> 8;                                                  \
    const size_t kb = (size_t)ch * KCH;                                        \
    const int lane  = tid & 63;                                                \
    const int wid   = tid >> 6;                                                \
    const int wm    = (wid & 1) * 64;                                          \
    const int wn    = (wid >> 1) * 64;                                         \
    const int row16 = lane & 15;                                               \
    const int quad  = lane >> 4;                                               \
    int aOff[4], bOff[4];                                                      \
    _Pragma("unroll") for (int mt = 0; mt < 4; ++mt) {                         \
        int r = wm + mt * 16 + row16;                                          \
        aOff[mt] = r * BK + ((quad ^ (r & 7)) * 8);                            \
    }                                                                          \
    _Pragma("unroll") for (int nt = 0; nt < 4; ++nt) {                         \
        int c = wn + nt * 16 + row16;                                          \
        bOff[nt] = c * BK + ((quad ^ (c & 7)) * 8);                            \
    }                                                                          \
    const int r0 = tid >> 3, s0 = tid & 7;                                     \
    const unsigned short* gA0 = A  + (size_t)(m0 + r0) * KD2 + kb              \
                                + ((s0 ^ (r0 & 7)) * 8);                       \
    const unsigned short* gB0 = Bt + (size_t)(n0 + r0) * KD2 + kb              \
                                + ((s0 ^ (r0 & 7)) * 8);                       \
    unsigned short* dA = lA + tid * 8;                                         \
    unsigned short* dB = lB + tid * 8;                                         \
    f32x4 acc[4][4] = {};                                                      \
    for (int k0 = 0; k0 < KCH; k0 += BK) {                                     \
        _Pragma("unroll") for (int j = 0; j < 4; ++j)                          \
            ld_lds16(gA0 + k0 + (size_t)j * 32 * KD2, dA + j * 2048);          \
        _Pragma("unroll") for (int j = 0; j < 4; ++j)                          \
            ld_lds16(gB0 + k0 + (size_t)j * 32 * KD2, dB + j * 2048);          \
        __syncthreads();                                                       \
        _Pragma("unroll") for (int kk = 0; kk < 2; ++kk) {                     \
            const int xo = kk * 32;                                            \
            bf16x8 aF[4], bF[4];                                               \
            _Pragma("unroll") for (int mt = 0; mt < 4; ++mt)                   \
                aF[mt] = *(const bf16x8*)(lA + (aOff[mt] ^ xo));               \
            _Pragma("unroll") for (int nt = 0; nt < 4; ++nt)                   \
                bF[nt] = *(const bf16x8*)(lB + (bOff[nt] ^ xo));               \
            _Pragma("unroll") for (int mt = 0; mt < 4; ++mt)                   \
                _Pragma("unroll") for (int nt = 0; nt < 4; ++nt)               \
                    acc[mt][nt] = __builtin_amdgcn_mfma_f32_16x16x32_bf16(     \
                        aF[mt], bF[nt], acc[mt][nt], 0, 0, 0);                 \
        }                                                                      \
        __syncthreads();                                                       \
    }                                                                          \
    if (ch == 0) {                                                             \
        float* sbw = (float*)lA;   /* safe: loop ended with __syncthreads */   \
        if (tid < BN) {                                                        \
            float s = 0.f;                                                     \
            _Pragma("unroll") for (int g = 0; g < 32; ++g)                     \
                s += bias_part[(size_t)g * OUT_DIM + n0 + tid];                \
            sbw[tid] = s;                                                      \
        }                                                                      \
        __syncthreads();                                                       \
    }                                                                          \
    const float* sb = (const float*)lA;                                        \
    __VA_ARGS__

// Plain-store variant (R6): ch==0 -> C (with bias); ch>0 -> Cp plane (ch-1).
// NO fences, NO flags — the reduce runs as its own dispatch.
__global__ __launch_bounds__(256, 4) void gemm_store(
    const unsigned short* __restrict__ A,    // bf16 bits [BATCH][KD2]
    const unsigned short* __restrict__ Bt,   // bf16 bits [OUT_DIM][KD2]
    const float* __restrict__ bias_part,     // [32][OUT_DIM]
    float* __restrict__ Cp,                  // [3][BATCH*OUT_DIM] partials
    float* __restrict__ C) {                 // [BATCH][OUT_DIM]
    GEMM_BODY(
        float* dst = (ch == 0) ? C : (Cp + (size_t)(ch - 1) * BATCH * OUT_DIM);
        _Pragma("unroll") for (int mt = 0; mt < 4; ++mt) {
            const int rbase = m0 + wm + mt * 16 + quad * 4;
            _Pragma("unroll") for (int nt = 0; nt < 4; ++nt) {
                const int col = n0 + wn + nt * 16 + row16;
                const float bv = (ch == 0) ? sb[wn + nt * 16 + row16] : 0.f;
                _Pragma("unroll") for (int r = 0; r < 4; ++r)
                    dst[(size_t)(rbase + r) * OUT_DIM + col] =
                        acc[mt][nt][r] + bv;
            }
        }
    )
}

// Atomic variant (fallback path).
__global__ __launch_bounds__(256, 4) void gemm_atomic(
    const unsigned short* __restrict__ A,
    const unsigned short* __restrict__ Bt,
    const float* __restrict__ bias_part,
    float* __restrict__ C) {                 // pre-zeroed
    GEMM_BODY(
        _Pragma("unroll") for (int mt = 0; mt < 4; ++mt) {
            const int rbase = m0 + wm + mt * 16 + quad * 4;
            _Pragma("unroll") for (int nt = 0; nt < 4; ++nt) {
                const int col = n0 + wn + nt * 16 + row16;
                const float bv = (ch == 0) ? sb[wn + nt * 16 + row16] : 0.f;
                _Pragma("unroll") for (int r = 0; r < 4; ++r)
                    atomicAdd(&C[(size_t)(rbase + r) * OUT_DIM + col],
                              acc[mt][nt][r] + bv);
            }
        }
    )
}

// ---------------------------------------------------------------------------
// Kernel 3: reduce — C += Cp1 + Cp2 + Cp3 (R6-identical). 80 MB ~ 13 us.
// ---------------------------------------------------------------------------
__global__ __launch_bounds__(256) void reduce_kernel(
    const float* __restrict__ Cp,   // [3][BATCH*OUT_DIM]
    float* __restrict__ C) {
    const size_t P = (size_t)BATCH * OUT_DIM;
    const size_t base = (size_t)blockIdx.x * 4096 + threadIdx.x * 4;
#pragma unroll
    for (int j = 0; j < 4; ++j) {
        const size_t idx = base + (size_t)j * 1024;
        f32x4 v  = *(const f32x4*)(C + idx);
        f32x4 v1 = *(const f32x4*)(Cp + idx);
        f32x4 v2 = *(const f32x4*)(Cp + P + idx);
        f32x4 v3 = *(const f32x4*)(Cp + 2 * P + idx);
        v = v + v1 + v2 + v3;
        *(f32x4*)(C + idx) = v;
    }
}

// ---------------------------------------------------------------------------
// Fallback (only if ws too small): fp32, block per batch row, basis in LDS.
// ---------------------------------------------------------------------------
__global__ __launch_bounds__(256) void fallback_kernel(
    const float* __restrict__ x, const float* __restrict__ ap,
    const float* __restrict__ qp, const float* __restrict__ coeffs,
    float* __restrict__ out) {
    __shared__ float sb[IN_DIM][NB];   // 32 KB
    const int b = blockIdx.x;
    const float a = ap[0], q = qp[0];
    for (int i = threadIdx.x; i < IN_DIM; i += 256) {
        float xt = fast_tanh(x[(size_t)b * IN_DIM + i]);
        float p0 = 1.0f, p1 = xt - a;
        sb[i][0] = p0; sb[i][1] = p1;
        float qn = q, qn1 = 1.0f;
#pragma unroll
        for (int n = 2; n < NB; ++n) {
            qn *= q; qn1 *= q;
            float p2 = (xt - (a + qn)) * p1 - a * qn1 * p0;
            sb[i][n] = p2;
            p0 = p1; p1 = p2;
        }
    }
    __syncthreads();
    float acc[4] = {0.f, 0.f, 0.f, 0.f};
    for (int i = 0; i < IN_DIM; ++i) {
        float bb[NB];
#pragma unroll
        for (int d = 0; d < NB; ++d) bb[d] = sb[i][d];
#pragma unroll
        for (int j = 0; j < 4; ++j) {
            int o = threadIdx.x + j * 256;
            const float* cf = coeffs + ((size_t)i * OUT_DIM + o) * NB;
            float s = 0.f;
#pragma unroll
            for (int d = 0; d < NB; ++d) s += bb[d] * cf[d];
            acc[j] += s;
        }
    }
#pragma unroll
    for (int j = 0; j < 4; ++j)
        out[(size_t)b * OUT_DIM + threadIdx.x + j * 256] = acc[j];
}

// ---------------------------------------------------------------------------
extern "C" void kernel_launch(void* const* d_in, const int* in_sizes, int n_in,
                              void* d_out, int out_size, void* d_ws, size_t ws_size,
                              hipStream_t stream) {
    const float* x      = (const float*)d_in[0];
    const float* a      = (const float*)d_in[1];
    const float* q      = (const float*)d_in[2];
    const float* coeffs = (const float*)d_in[3];
    float* out = (float*)d_out;

    const size_t needA = (size_t)BATCH * KD2 * sizeof(unsigned short);   // 56 MB
    const size_t needB = (size_t)OUT_DIM * KD2 * sizeof(unsigned short); // 14 MB
    const size_t needBias = 32 * (size_t)OUT_DIM * sizeof(float);        // 128 KB
    const size_t needCp = 3 * (size_t)BATCH * OUT_DIM * sizeof(float);   // 48 MB

    if (ws_size >= needA + needB + needBias + needCp) {
        // Preferred path (R6 structure, 3 dispatches): prep -> gemm -> reduce.
        unsigned short* Aw = (unsigned short*)d_ws;
        unsigned short* Bt = Aw + (size_t)BATCH * KD2;
        float* bias_part = (float*)((char*)d_ws + needA + needB);
        float* Cp = (float*)((char*)d_ws + needA + needB + needBias);
        prep_kernel<<<PREP_BLOCKS, 256, 0, stream>>>(
            x, a, q, coeffs, Aw, Bt, bias_part);
        gemm_store<<<(BATCH / BM) * (OUT_DIM / BN) * KSPLIT, 256, 0, stream>>>(
            Aw, Bt, bias_part, Cp, out);
        reduce_kernel<<<BATCH * OUT_DIM / 4096, 256, 0, stream>>>(Cp, out);
    } else if (ws_size >= needA + needB + needBias) {
        // Atomic path (known-good ~202 us).
        unsigned short* Aw = (unsigned short*)d_ws;
        unsigned short* Bt = Aw + (size_t)BATCH * KD2;
        float* bias_part = (float*)((char*)d_ws + needA + needB);
        prep_kernel<<<PREP_BLOCKS, 256, 0, stream>>>(
            x, a, q, coeffs, Aw, Bt, bias_part);
        zero_kernel<<<ZERO_BLOCKS, 256, 0, stream>>>(out);
        gemm_atomic<<<(BATCH / BM) * (OUT_DIM / BN) * KSPLIT, 256, 0, stream>>>(
            Aw, Bt, bias_part, out);
    } else {
        fallback_kernel<<<BATCH, 256, 0, stream>>>(x, a, q, coeffs, out);
    }
}

// Round 9
// 172.320 us; speedup vs baseline: 2.1763x; 1.0256x over previous
//
#include <hip/hip_runtime.h>

#define BATCH   4096
#define IN_DIM  1024
#define OUT_DIM 1024
#define NB      8                 // DEGREE + 1
#define NBK     7                 // basis funcs in the GEMM (d=1..7; d=0 is a bias)
#define KD2     (IN_DIM * NBK)    // 7168
// Workspace K-layout (d-major): k = (d-1)*IN_DIM + i, for BOTH A and Bt.
// R5 lesson: hipLaunchCooperativeKernel is NOT graph-capturable here (hang x2).
// R7 lesson: device-scope __threadfence in a hot kernel -> L2 writeback storm
// on non-coherent-XCD hardware (FETCH +46 MB, 4x slowdown). Keep cross-block
// dataflow in separate dispatches.
// R8 state: gemm 66 us (= m97-structure ceiling ~912 TF), prep ~28, reduce
// ~13, fixed harness overhead ~70. This round: gemm block->XCD remap only.
// The old mapping (all 4 K-chunks of a tile on one XCD) served the atomics,
// which are gone since R6. New mapping: XCD = (ch, m-half) -> per-XCD
// working set 44 MB -> 10.7 MB (16 A-panels + 8 B-panels, one K-chunk).

typedef __bf16 bf16x8 __attribute__((ext_vector_type(8)));
typedef float  f32x4  __attribute__((ext_vector_type(4)));
typedef unsigned short us8 __attribute__((ext_vector_type(8)));
typedef unsigned short us4 __attribute__((ext_vector_type(4)));

__device__ __forceinline__ unsigned short f2bf(float f) {
    unsigned int u = __float_as_uint(f);
    u += 0x7fffu + ((u >> 16) & 1u);   // round-to-nearest-even
    return (unsigned short)(u >> 16);
}

// fast tanh: 1 - 2/(e^{2x}+1) via v_exp_f32 + v_rcp_f32; exact limits at +-inf.
__device__ __forceinline__ float fast_tanh(float x) {
    const float LOG2E_X2 = 2.8853900817779268f;   // 2*log2(e)
    float e = __builtin_amdgcn_exp2f(x * LOG2E_X2);
    return 1.0f - 2.0f * __builtin_amdgcn_rcpf(e + 1.0f);
}

__device__ __forceinline__ void ld_lds16(const unsigned short* g, unsigned short* l) {
    __builtin_amdgcn_global_load_lds(
        (const __attribute__((address_space(1))) void*)g,
        (__attribute__((address_space(3))) void*)l, 16, 0, 0);
}

// ---------------------------------------------------------------------------
// Kernel 1: fused prep (basis + repack), two block-role ranges. UNCHANGED (R8).
//  [0, 512):      coeffs repack patch (heavier; scheduled first) + fp32 bias
//  [512, 2560):   basis rows, 2 rows/block (float4 loads up front, fp32
//                 recurrence, 7x us8 16B stores per d-plane)
// ---------------------------------------------------------------------------
#define REPACK_BLOCKS 512
#define BASIS_BLOCKS  (BATCH / 2)              // 2048
#define PREP_BLOCKS   (REPACK_BLOCKS + BASIS_BLOCKS)
#define TI 32
#define TO 64
#define RSTR 232    // LDS row stride (ushorts) per o: 224 data + 8 pad

__global__ __launch_bounds__(256) void prep_kernel(
    const float* __restrict__ x, const float* __restrict__ ap,
    const float* __restrict__ qp, const float* __restrict__ coeffs,
    unsigned short* __restrict__ Aw, unsigned short* __restrict__ Bt,
    float* __restrict__ bias_part) {  // [32][OUT_DIM]
    __shared__ __align__(16) unsigned short lt[TO * RSTR + 512];  // 30.0 KB
    const int tid = threadIdx.x;

    if (blockIdx.x < REPACK_BLOCKS) {
        // ---- repack + bias partials: patch i0..i0+32 x o0..o0+64 ----
        const int bid = blockIdx.x;
        const int g  = bid & 31;
        const int i0 = g * TI;
        const int o0 = (bid >> 5) * TO;
        const int o_local = tid & 63;
        float bpart = 0.f;
#pragma unroll
        for (int pass = 0; pass < 8; ++pass) {
            const int i_local = pass * 4 + (tid >> 6);
            const float* src = coeffs +
                ((size_t)(i0 + i_local) * OUT_DIM + (o0 + o_local)) * NB;
            float4 v0 = *(const float4*)src;
            float4 v1 = *(const float4*)(src + 4);
            bpart += v0.x;                       // d = 0 -> exact fp32 bias
            // LDS stage, d-major per o: lt[o][d-1][i_local] (stride 32 per d)
            unsigned short* dst = lt + o_local * RSTR + i_local;
            dst[0]   = f2bf(v0.y); dst[32]  = f2bf(v0.z); dst[64]  = f2bf(v0.w);
            dst[96]  = f2bf(v1.x); dst[128] = f2bf(v1.y); dst[160] = f2bf(v1.z);
            dst[192] = f2bf(v1.w);
        }
        float* sb = (float*)(lt + TO * RSTR);    // 256 floats
        sb[(tid >> 6) * 64 + o_local] = bpart;
        __syncthreads();
        if (tid < 64)
            bias_part[(size_t)g * OUT_DIM + o0 + tid] =
                sb[tid] + sb[64 + tid] + sb[128 + tid] + sb[192 + tid];
        // write phase: thread -> (o = tid>>2, c = tid&3); 7 d-groups of 64B
#pragma unroll
        for (int p = 0; p < 7; ++p) {
            const int o = tid >> 2;
            const int c = tid & 3;
            us8 v = *(const us8*)(lt + o * RSTR + p * 32 + c * 8);
            *(us8*)(Bt + (size_t)(o0 + o) * KD2 + (size_t)p * IN_DIM + i0 + c * 8) = v;
        }
        return;
    }

    // ---- basis: 2 rows/block; thread owns 8 contiguous i of one row ----
    const int bb  = blockIdx.x - REPACK_BLOCKS;
    const float a = ap[0], q = qp[0];
    const int b  = bb * 2 + (tid >> 7);
    const int i0 = (tid & 127) * 8;

    const float* xs = x + (size_t)b * IN_DIM + i0;
    float4 v0 = *(const float4*)xs;          // both loads issued before any use
    float4 v1 = *(const float4*)(xs + 4);

    float xe[8] = {v0.x, v0.y, v0.z, v0.w, v1.x, v1.y, v1.z, v1.w};
    float pm2[8], pm1[8];
    us8 ov;
#pragma unroll
    for (int e = 0; e < 8; ++e) {
        xe[e] = fast_tanh(xe[e]);
        pm2[e] = 1.0f;
        pm1[e] = xe[e] - a;
        ov[e] = f2bf(pm1[e]);
    }
    unsigned short* arow = Aw + (size_t)b * KD2 + i0;
    *(us8*)arow = ov;                         // d=1 plane
    float qn = q, qn1 = 1.0f;
#pragma unroll
    for (int n = 2; n < NB; ++n) {
        qn *= q; qn1 *= q;
#pragma unroll
        for (int e = 0; e < 8; ++e) {
            float pn = (xe[e] - (a + qn)) * pm1[e] - a * qn1 * pm2[e];
            pm2[e] = pm1[e]; pm1[e] = pn;
            ov[e] = f2bf(pn);
        }
        *(us8*)(arow + (size_t)(n - 1) * IN_DIM) = ov;   // d=n plane, 16 B
    }
}

// ---------------------------------------------------------------------------
// zero C — used ONLY by the atomic fallback path.
// ---------------------------------------------------------------------------
#define ZERO_BLOCKS   (BATCH * OUT_DIM / 4096) // 1024

__global__ __launch_bounds__(256) void zero_kernel(float* __restrict__ C) {
    float* dst = C + (size_t)blockIdx.x * 4096 + threadIdx.x * 4;
    const f32x4 zero = {0.f, 0.f, 0.f, 0.f};
#pragma unroll
    for (int j = 0; j < 4; ++j) *(f32x4*)(dst + j * 1024) = zero;
}

// ---------------------------------------------------------------------------
// Shared GEMM geometry (proven 128x128 body). Variadic macro so epilogue
// commas are safe.
// NEW mapping (R9): bidx = 8*loc + (ch*2 + mhalf);  loc = mloc*8 + nloc.
//   XCD (bidx&7) <-> (ch, m-half): each XCD runs 16 m-tiles x 8 n-tiles of
//   ONE K-chunk -> unique panel footprint 10.7 MB (was 44 MB). m-outer /
//   n-inner within the group keeps one A-panel resident while B cycles.
// ---------------------------------------------------------------------------
#define BM 128
#define BN 128
#define BK 64
#define KSPLIT 4
#define KCH (KD2 / KSPLIT)   // 1792 -> 28 iters of BK=64

#define GEMM_BODY(...)                                                         \
    __shared__ __align__(16) unsigned short lA[BM * BK];  /* 16 KB */          \
    __shared__ __align__(16) unsigned short lB[BN * BK];  /* 16 KB */          \
    const int tid  = threadIdx.x;                                              \
    const int bidx = blockIdx.x;                                               \
    const int ch    = (bidx & 7) >> 1;                                         \
    const int mhalf = bidx & 1;                                                \
    const int loc   = bidx >> 3;                                               \
    const int m0 = ((loc >> 3) + mhalf * 16) * BM;                             \
    const int n0 = (loc & 7) * BN;                                             \
    const size_t kb = (size_t)ch * KCH;                                        \
    const int lane  = tid & 63;                                                \
    const int wid   = tid >> 6;                                                \
    const int wm    = (wid & 1) * 64;                                          \
    const int wn    = (wid >> 1) * 64;                                         \
    const int row16 = lane & 15;                                               \
    const int quad  = lane >> 4;                                               \
    int aOff[4], bOff[4];                                                      \
    _Pragma("unroll") for (int mt = 0; mt < 4; ++mt) {                         \
        int r = wm + mt * 16 + row16;                                          \
        aOff[mt] = r * BK + ((quad ^ (r & 7)) * 8);                            \
    }                                                                          \
    _Pragma("unroll") for (int nt = 0; nt < 4; ++nt) {                         \
        int c = wn + nt * 16 + row16;                                          \
        bOff[nt] = c * BK + ((quad ^ (c & 7)) * 8);                            \
    }                                                                          \
    const int r0 = tid >> 3, s0 = tid & 7;                                     \
    const unsigned short* gA0 = A  + (size_t)(m0 + r0) * KD2 + kb              \
                                + ((s0 ^ (r0 & 7)) * 8);                       \
    const unsigned short* gB0 = Bt + (size_t)(n0 + r0) * KD2 + kb              \
                                + ((s0 ^ (r0 & 7)) * 8);                       \
    unsigned short* dA = lA + tid * 8;                                         \
    unsigned short* dB = lB + tid * 8;                                         \
    f32x4 acc[4][4] = {};                                                      \
    for (int k0 = 0; k0 < KCH; k0 += BK) {                                     \
        _Pragma("unroll") for (int j = 0; j < 4; ++j)                          \
            ld_lds16(gA0 + k0 + (size_t)j * 32 * KD2, dA + j * 2048);          \
        _Pragma("unroll") for (int j = 0; j < 4; ++j)                          \
            ld_lds16(gB0 + k0 + (size_t)j * 32 * KD2, dB + j * 2048);          \
        __syncthreads();                                                       \
        _Pragma("unroll") for (int kk = 0; kk < 2; ++kk) {                     \
            const int xo = kk * 32;                                            \
            bf16x8 aF[4], bF[4];                                               \
            _Pragma("unroll") for (int mt = 0; mt < 4; ++mt)                   \
                aF[mt] = *(const bf16x8*)(lA + (aOff[mt] ^ xo));               \
            _Pragma("unroll") for (int nt = 0; nt < 4; ++nt)                   \
                bF[nt] = *(const bf16x8*)(lB + (bOff[nt] ^ xo));               \
            _Pragma("unroll") for (int mt = 0; mt < 4; ++mt)                   \
                _Pragma("unroll") for (int nt = 0; nt < 4; ++nt)               \
                    acc[mt][nt] = __builtin_amdgcn_mfma_f32_16x16x32_bf16(     \
                        aF[mt], bF[nt], acc[mt][nt], 0, 0, 0);                 \
        }                                                                      \
        __syncthreads();                                                       \
    }                                                                          \
    if (ch == 0) {                                                             \
        float* sbw = (float*)lA;   /* safe: loop ended with __syncthreads */   \
        if (tid < BN) {                                                        \
            float s = 0.f;                                                     \
            _Pragma("unroll") for (int g = 0; g < 32; ++g)                     \
                s += bias_part[(size_t)g * OUT_DIM + n0 + tid];                \
            sbw[tid] = s;                                                      \
        }                                                                      \
        __syncthreads();                                                       \
    }                                                                          \
    const float* sb = (const float*)lA;                                        \
    __VA_ARGS__

// Plain-store variant (R6): ch==0 -> C (with bias); ch>0 -> Cp plane (ch-1).
// NO fences, NO flags — the reduce runs as its own dispatch.
__global__ __launch_bounds__(256, 4) void gemm_store(
    const unsigned short* __restrict__ A,    // bf16 bits [BATCH][KD2]
    const unsigned short* __restrict__ Bt,   // bf16 bits [OUT_DIM][KD2]
    const float* __restrict__ bias_part,     // [32][OUT_DIM]
    float* __restrict__ Cp,                  // [3][BATCH*OUT_DIM] partials
    float* __restrict__ C) {                 // [BATCH][OUT_DIM]
    GEMM_BODY(
        float* dst = (ch == 0) ? C : (Cp + (size_t)(ch - 1) * BATCH * OUT_DIM);
        _Pragma("unroll") for (int mt = 0; mt < 4; ++mt) {
            const int rbase = m0 + wm + mt * 16 + quad * 4;
            _Pragma("unroll") for (int nt = 0; nt < 4; ++nt) {
                const int col = n0 + wn + nt * 16 + row16;
                const float bv = (ch == 0) ? sb[wn + nt * 16 + row16] : 0.f;
                _Pragma("unroll") for (int r = 0; r < 4; ++r)
                    dst[(size_t)(rbase + r) * OUT_DIM + col] =
                        acc[mt][nt][r] + bv;
            }
        }
    )
}

// Atomic variant (fallback path).
__global__ __launch_bounds__(256, 4) void gemm_atomic(
    const unsigned short* __restrict__ A,
    const unsigned short* __restrict__ Bt,
    const float* __restrict__ bias_part,
    float* __restrict__ C) {                 // pre-zeroed
    GEMM_BODY(
        _Pragma("unroll") for (int mt = 0; mt < 4; ++mt) {
            const int rbase = m0 + wm + mt * 16 + quad * 4;
            _Pragma("unroll") for (int nt = 0; nt < 4; ++nt) {
                const int col = n0 + wn + nt * 16 + row16;
                const float bv = (ch == 0) ? sb[wn + nt * 16 + row16] : 0.f;
                _Pragma("unroll") for (int r = 0; r < 4; ++r)
                    atomicAdd(&C[(size_t)(rbase + r) * OUT_DIM + col],
                              acc[mt][nt][r] + bv);
            }
        }
    )
}

// ---------------------------------------------------------------------------
// Kernel 3: reduce — C += Cp1 + Cp2 + Cp3 (R6-identical). 80 MB ~ 13 us.
// ---------------------------------------------------------------------------
__global__ __launch_bounds__(256) void reduce_kernel(
    const float* __restrict__ Cp,   // [3][BATCH*OUT_DIM]
    float* __restrict__ C) {
    const size_t P = (size_t)BATCH * OUT_DIM;
    const size_t base = (size_t)blockIdx.x * 4096 + threadIdx.x * 4;
#pragma unroll
    for (int j = 0; j < 4; ++j) {
        const size_t idx = base + (size_t)j * 1024;
        f32x4 v  = *(const f32x4*)(C + idx);
        f32x4 v1 = *(const f32x4*)(Cp + idx);
        f32x4 v2 = *(const f32x4*)(Cp + P + idx);
        f32x4 v3 = *(const f32x4*)(Cp + 2 * P + idx);
        v = v + v1 + v2 + v3;
        *(f32x4*)(C + idx) = v;
    }
}

// ---------------------------------------------------------------------------
// Fallback (only if ws too small): fp32, block per batch row, basis in LDS.
// ---------------------------------------------------------------------------
__global__ __launch_bounds__(256) void fallback_kernel(
    const float* __restrict__ x, const float* __restrict__ ap,
    const float* __restrict__ qp, const float* __restrict__ coeffs,
    float* __restrict__ out) {
    __shared__ float sb[IN_DIM][NB];   // 32 KB
    const int b = blockIdx.x;
    const float a = ap[0], q = qp[0];
    for (int i = threadIdx.x; i < IN_DIM; i += 256) {
        float xt = fast_tanh(x[(size_t)b * IN_DIM + i]);
        float p0 = 1.0f, p1 = xt - a;
        sb[i][0] = p0; sb[i][1] = p1;
        float qn = q, qn1 = 1.0f;
#pragma unroll
        for (int n = 2; n < NB; ++n) {
            qn *= q; qn1 *= q;
            float p2 = (xt - (a + qn)) * p1 - a * qn1 * p0;
            sb[i][n] = p2;
            p0 = p1; p1 = p2;
        }
    }
    __syncthreads();
    float acc[4] = {0.f, 0.f, 0.f, 0.f};
    for (int i = 0; i < IN_DIM; ++i) {
        float bb[NB];
#pragma unroll
        for (int d = 0; d < NB; ++d) bb[d] = sb[i][d];
#pragma unroll
        for (int j = 0; j < 4; ++j) {
            int o = threadIdx.x + j * 256;
            const float* cf = coeffs + ((size_t)i * OUT_DIM + o) * NB;
            float s = 0.f;
#pragma unroll
            for (int d = 0; d < NB; ++d) s += bb[d] * cf[d];
            acc[j] += s;
        }
    }
#pragma unroll
    for (int j = 0; j < 4; ++j)
        out[(size_t)b * OUT_DIM + threadIdx.x + j * 256] = acc[j];
}

// ---------------------------------------------------------------------------
extern "C" void kernel_launch(void* const* d_in, const int* in_sizes, int n_in,
                              void* d_out, int out_size, void* d_ws, size_t ws_size,
                              hipStream_t stream) {
    const float* x      = (const float*)d_in[0];
    const float* a      = (const float*)d_in[1];
    const float* q      = (const float*)d_in[2];
    const float* coeffs = (const float*)d_in[3];
    float* out = (float*)d_out;

    const size_t needA = (size_t)BATCH * KD2 * sizeof(unsigned short);   // 56 MB
    const size_t needB = (size_t)OUT_DIM * KD2 * sizeof(unsigned short); // 14 MB
    const size_t needBias = 32 * (size_t)OUT_DIM * sizeof(float);        // 128 KB
    const size_t needCp = 3 * (size_t)BATCH * OUT_DIM * sizeof(float);   // 48 MB

    if (ws_size >= needA + needB + needBias + needCp) {
        // Preferred path (3 dispatches): prep -> gemm -> reduce.
        unsigned short* Aw = (unsigned short*)d_ws;
        unsigned short* Bt = Aw + (size_t)BATCH * KD2;
        float* bias_part = (float*)((char*)d_ws + needA + needB);
        float* Cp = (float*)((char*)d_ws + needA + needB + needBias);
        prep_kernel<<<PREP_BLOCKS, 256, 0, stream>>>(
            x, a, q, coeffs, Aw, Bt, bias_part);
        gemm_store<<<(BATCH / BM) * (OUT_DIM / BN) * KSPLIT, 256, 0, stream>>>(
            Aw, Bt, bias_part, Cp, out);
        reduce_kernel<<<BATCH * OUT_DIM / 4096, 256, 0, stream>>>(Cp, out);
    } else if (ws_size >= needA + needB + needBias) {
        // Atomic path (known-good ~202 us).
        unsigned short* Aw = (unsigned short*)d_ws;
        unsigned short* Bt = Aw + (size_t)BATCH * KD2;
        float* bias_part = (float*)((char*)d_ws + needA + needB);
        prep_kernel<<<PREP_BLOCKS, 256, 0, stream>>>(
            x, a, q, coeffs, Aw, Bt, bias_part);
        zero_kernel<<<ZERO_BLOCKS, 256, 0, stream>>>(out);
        gemm_atomic<<<(BATCH / BM) * (OUT_DIM / BN) * KSPLIT, 256, 0, stream>>>(
            Aw, Bt, bias_part, out);
    } else {
        fallback_kernel<<<BATCH, 256, 0, stream>>>(x, a, q, coeffs, out);
    }
}

// Round 10
// 168.173 us; speedup vs baseline: 2.2299x; 1.0247x over previous
//
#include <hip/hip_runtime.h>

#define BATCH   4096
#define IN_DIM  1024
#define OUT_DIM 1024
#define NB      8                 // DEGREE + 1
#define NBK     7                 // basis funcs in the GEMM (d=1..7; d=0 is a bias)
#define KD2     (IN_DIM * NBK)    // 7168
// Workspace K-layout (d-major): k = (d-1)*IN_DIM + i, for BOTH A and Bt.
// R5 lesson: hipLaunchCooperativeKernel is NOT graph-capturable here (hang x2).
// R7 lesson: device-scope __threadfence in a hot kernel -> L2 writeback storm.
// R6 lesson: split-K atomics cost ~28 us -> plain stores + separate reduce.
// R9 lesson: XCD = (ch, m-half) remap -> FETCH -40%, gemm 62 us.
// R10: the R1/R2 8-phase "failures" were confounded by the atomic epilogue
// (tail ~49 us at 1 blk/CU). Retry the verified R2 8-phase K-loop with the
// R6 store epilogue + R9-style XCD map. Revert target if this regresses: R9.

typedef __bf16 bf16x8 __attribute__((ext_vector_type(8)));
typedef float  f32x4  __attribute__((ext_vector_type(4)));
typedef unsigned short us8 __attribute__((ext_vector_type(8)));
typedef unsigned short us4 __attribute__((ext_vector_type(4)));

__device__ __forceinline__ unsigned short f2bf(float f) {
    unsigned int u = __float_as_uint(f);
    u += 0x7fffu + ((u >> 16) & 1u);   // round-to-nearest-even
    return (unsigned short)(u >> 16);
}

// fast tanh: 1 - 2/(e^{2x}+1) via v_exp_f32 + v_rcp_f32; exact limits at +-inf.
__device__ __forceinline__ float fast_tanh(float x) {
    const float LOG2E_X2 = 2.8853900817779268f;   // 2*log2(e)
    float e = __builtin_amdgcn_exp2f(x * LOG2E_X2);
    return 1.0f - 2.0f * __builtin_amdgcn_rcpf(e + 1.0f);
}

__device__ __forceinline__ void ld_lds16(const unsigned short* g, unsigned short* l) {
    __builtin_amdgcn_global_load_lds(
        (const __attribute__((address_space(1))) void*)g,
        (__attribute__((address_space(3))) void*)l, 16, 0, 0);
}

// 32-bit LDS offset of a generic pointer that points into LDS.
__device__ __forceinline__ unsigned lds_off(const void* p) {
    return (unsigned)(unsigned long long)
        (const __attribute__((address_space(3))) void*)p;
}

// Inline-asm ds_read_b128: opaque to SIInsertWaitcnts so the compiler can't
// graft conservative vmcnt waits (LDS-DMA aliasing) onto the counted-vmcnt
// pipeline. Ordering is explicit: barrier -> lgkmcnt(0) -> sched_barrier(0).
template <int OFF>
__device__ __forceinline__ bf16x8 dsr128(unsigned addr) {
    f32x4 r;
    asm volatile("ds_read_b128 %0, %1 offset:%c2"
                 : "=v"(r) : "v"(addr), "i"(OFF));
    union { f32x4 f; bf16x8 h; } u; u.f = r; return u.h;
}

// ---------------------------------------------------------------------------
// Kernel 1: fused prep (basis + repack), two block-role ranges. UNCHANGED (R9).
// ---------------------------------------------------------------------------
#define REPACK_BLOCKS 512
#define BASIS_BLOCKS  (BATCH / 2)              // 2048
#define PREP_BLOCKS   (REPACK_BLOCKS + BASIS_BLOCKS)
#define TI 32
#define TO 64
#define RSTR 232    // LDS row stride (ushorts) per o: 224 data + 8 pad

__global__ __launch_bounds__(256) void prep_kernel(
    const float* __restrict__ x, const float* __restrict__ ap,
    const float* __restrict__ qp, const float* __restrict__ coeffs,
    unsigned short* __restrict__ Aw, unsigned short* __restrict__ Bt,
    float* __restrict__ bias_part) {  // [32][OUT_DIM]
    __shared__ __align__(16) unsigned short lt[TO * RSTR + 512];  // 30.0 KB
    const int tid = threadIdx.x;

    if (blockIdx.x < REPACK_BLOCKS) {
        // ---- repack + bias partials: patch i0..i0+32 x o0..o0+64 ----
        const int bid = blockIdx.x;
        const int g  = bid & 31;
        const int i0 = g * TI;
        const int o0 = (bid >> 5) * TO;
        const int o_local = tid & 63;
        float bpart = 0.f;
#pragma unroll
        for (int pass = 0; pass < 8; ++pass) {
            const int i_local = pass * 4 + (tid >> 6);
            const float* src = coeffs +
                ((size_t)(i0 + i_local) * OUT_DIM + (o0 + o_local)) * NB;
            float4 v0 = *(const float4*)src;
            float4 v1 = *(const float4*)(src + 4);
            bpart += v0.x;                       // d = 0 -> exact fp32 bias
            unsigned short* dst = lt + o_local * RSTR + i_local;
            dst[0]   = f2bf(v0.y); dst[32]  = f2bf(v0.z); dst[64]  = f2bf(v0.w);
            dst[96]  = f2bf(v1.x); dst[128] = f2bf(v1.y); dst[160] = f2bf(v1.z);
            dst[192] = f2bf(v1.w);
        }
        float* sb = (float*)(lt + TO * RSTR);    // 256 floats
        sb[(tid >> 6) * 64 + o_local] = bpart;
        __syncthreads();
        if (tid < 64)
            bias_part[(size_t)g * OUT_DIM + o0 + tid] =
                sb[tid] + sb[64 + tid] + sb[128 + tid] + sb[192 + tid];
#pragma unroll
        for (int p = 0; p < 7; ++p) {
            const int o = tid >> 2;
            const int c = tid & 3;
            us8 v = *(const us8*)(lt + o * RSTR + p * 32 + c * 8);
            *(us8*)(Bt + (size_t)(o0 + o) * KD2 + (size_t)p * IN_DIM + i0 + c * 8) = v;
        }
        return;
    }

    // ---- basis: 2 rows/block; thread owns 8 contiguous i of one row ----
    const int bb  = blockIdx.x - REPACK_BLOCKS;
    const float a = ap[0], q = qp[0];
    const int b  = bb * 2 + (tid >> 7);
    const int i0 = (tid & 127) * 8;

    const float* xs = x + (size_t)b * IN_DIM + i0;
    float4 v0 = *(const float4*)xs;          // both loads issued before any use
    float4 v1 = *(const float4*)(xs + 4);

    float xe[8] = {v0.x, v0.y, v0.z, v0.w, v1.x, v1.y, v1.z, v1.w};
    float pm2[8], pm1[8];
    us8 ov;
#pragma unroll
    for (int e = 0; e < 8; ++e) {
        xe[e] = fast_tanh(xe[e]);
        pm2[e] = 1.0f;
        pm1[e] = xe[e] - a;
        ov[e] = f2bf(pm1[e]);
    }
    unsigned short* arow = Aw + (size_t)b * KD2 + i0;
    *(us8*)arow = ov;                         // d=1 plane
    float qn = q, qn1 = 1.0f;
#pragma unroll
    for (int n = 2; n < NB; ++n) {
        qn *= q; qn1 *= q;
#pragma unroll
        for (int e = 0; e < 8; ++e) {
            float pn = (xe[e] - (a + qn)) * pm1[e] - a * qn1 * pm2[e];
            pm2[e] = pm1[e]; pm1[e] = pn;
            ov[e] = f2bf(pn);
        }
        *(us8*)(arow + (size_t)(n - 1) * IN_DIM) = ov;   // d=n plane, 16 B
    }
}

// ---------------------------------------------------------------------------
// zero C — used ONLY by the atomic fallback path.
// ---------------------------------------------------------------------------
#define ZERO_BLOCKS   (BATCH * OUT_DIM / 4096) // 1024

__global__ __launch_bounds__(256) void zero_kernel(float* __restrict__ C) {
    float* dst = C + (size_t)blockIdx.x * 4096 + threadIdx.x * 4;
    const f32x4 zero = {0.f, 0.f, 0.f, 0.f};
#pragma unroll
    for (int j = 0; j < 4; ++j) *(f32x4*)(dst + j * 1024) = zero;
}

#define KSPLIT 4
#define KCH (KD2 / KSPLIT)   // 1792

// ---------------------------------------------------------------------------
// Kernel 2 (preferred): 256x256 8-phase counted-vmcnt GEMM, store epilogue.
// R2's verified schedule (refcheck'd; vmcnt/L-region math re-audited:
// P0/P1 read A L0,L2 + B; P2/P3 read A L1,L3; vmcnt(10)@P1-end guards P2;
// vmcnt(8)@P3-end guards next-tile P0). 512 thr = 8 waves (2M x 4N),
// per-wave C = 128x64; LDS 128 KiB dynamic, double-buffered.
// XCD map (R9 concept): bidx&7 = (ch*2 + mhalf); per-XCD footprint ~11 MB.
// Epilogue (R6): ch==0 -> C (+exact fp32 bias); ch=1..3 -> Cp planes.
// ---------------------------------------------------------------------------
#define BM2 256
#define BN2 256
#define BK2 64
#define NT  (KCH / BK2)      // 28 K-tiles per chunk
#define GEMM_LDS 131072

#define ISSUE_A(TT_, SL_, L_)                                                  \
    ld_lds16(gA + (size_t)(L_) * 64 * KD2 +                                    \
                 (size_t)((TT_) < NT ? (TT_) : (NT - 1)) * 64,                 \
             lds + (SL_) * 16384 + (L_) * 4096 + tid * 8)

#define ISSUE_B(TT_, SL_, L_)                                                  \
    ld_lds16(gB + (size_t)(L_) * 64 * KD2 +                                    \
                 (size_t)((TT_) < NT ? (TT_) : (NT - 1)) * 64,                 \
             lds + 32768 + (SL_) * 16384 + (L_) * 4096 + tid * 8)

#define BARRIER_A()                                                            \
    __builtin_amdgcn_s_barrier();                                              \
    asm volatile("s_waitcnt lgkmcnt(0)" ::: "memory");                         \
    __builtin_amdgcn_sched_barrier(0);

#define MFMA16(M_, A0_, A1_, A2_, A3_)                                         \
    __builtin_amdgcn_s_setprio(1);                                             \
    _Pragma("unroll") for (int nf = 0; nf < 4; ++nf) {                         \
        acc[M_][nf] = __builtin_amdgcn_mfma_f32_16x16x32_bf16(                 \
            A0_, bF[nf][0], acc[M_][nf], 0, 0, 0);                             \
        acc[M_][nf] = __builtin_amdgcn_mfma_f32_16x16x32_bf16(                 \
            A1_, bF[nf][1], acc[M_][nf], 0, 0, 0);                             \
        acc[(M_) + 1][nf] = __builtin_amdgcn_mfma_f32_16x16x32_bf16(           \
            A2_, bF[nf][0], acc[(M_) + 1][nf], 0, 0, 0);                       \
        acc[(M_) + 1][nf] = __builtin_amdgcn_mfma_f32_16x16x32_bf16(           \
            A3_, bF[nf][1], acc[(M_) + 1][nf], 0, 0, 0);                       \
    }                                                                          \
    __builtin_amdgcn_s_setprio(0);                                             \
    __builtin_amdgcn_sched_barrier(0);

#define TILE_BODY(T_, P_)                                                      \
    {                                                                          \
        constexpr int OFF = (P_) * 32768;                                      \
        { /* ---- P0 ---- */                                                   \
            bf16x8 a0 = dsr128<OFF>(aA[0]), a1 = dsr128<OFF>(aA[0] ^ 64);      \
            bf16x8 a2 = dsr128<OFF>(aA[1]), a3 = dsr128<OFF>(aA[1] ^ 64);      \
            _Pragma("unroll") for (int nf = 0; nf < 4; ++nf) {                 \
                bF[nf][0] = dsr128<OFF>(bA[nf]);                               \
                bF[nf][1] = dsr128<OFF>(bA[nf] ^ 64);                          \
            }                                                                  \
            ISSUE_A((T_) + 1, (P_) ^ 1, 1);                                    \
            ISSUE_A((T_) + 1, (P_) ^ 1, 3);                                    \
            BARRIER_A()                                                        \
            MFMA16(0, a0, a1, a2, a3)                                          \
            __builtin_amdgcn_s_barrier();                                      \
        }                                                                      \
        { /* ---- P1 ---- */                                                   \
            bf16x8 a0 = dsr128<OFF>(aA[2]), a1 = dsr128<OFF>(aA[2] ^ 64);      \
            bf16x8 a2 = dsr128<OFF>(aA[3]), a3 = dsr128<OFF>(aA[3] ^ 64);      \
            ISSUE_B((T_) + 2, (P_), 0);                                        \
            ISSUE_B((T_) + 2, (P_), 1);                                        \
            BARRIER_A()                                                        \
            MFMA16(2, a0, a1, a2, a3)                                          \
            asm volatile("s_waitcnt vmcnt(10)" ::: "memory");                  \
            __builtin_amdgcn_s_barrier();                                      \
        }                                                                      \
        { /* ---- P2 ---- */                                                   \
            bf16x8 a0 = dsr128<OFF>(aA[4]), a1 = dsr128<OFF>(aA[4] ^ 64);      \
            bf16x8 a2 = dsr128<OFF>(aA[5]), a3 = dsr128<OFF>(aA[5] ^ 64);      \
            ISSUE_B((T_) + 2, (P_), 2);                                        \
            ISSUE_B((T_) + 2, (P_), 3);                                        \
            BARRIER_A()                                                        \
            MFMA16(4, a0, a1, a2, a3)                                          \
            __builtin_amdgcn_s_barrier();                                      \
        }                                                                      \
        { /* ---- P3 ---- */                                                   \
            bf16x8 a0 = dsr128<OFF>(aA[6]), a1 = dsr128<OFF>(aA[6] ^ 64);      \
            bf16x8 a2 = dsr128<OFF>(aA[7]), a3 = dsr128<OFF>(aA[7] ^ 64);      \
            ISSUE_A((T_) + 2, (P_), 0);                                        \
            ISSUE_A((T_) + 2, (P_), 2);                                        \
            BARRIER_A()                                                        \
            MFMA16(6, a0, a1, a2, a3)                                          \
            asm volatile("s_waitcnt vmcnt(8)" ::: "memory");                   \
            __builtin_amdgcn_s_barrier();                                      \
        }                                                                      \
    }

__global__ __launch_bounds__(512, 2) void gemm8_store(
    const unsigned short* __restrict__ A,    // bf16 bits [BATCH][KD2]
    const unsigned short* __restrict__ Bt,   // bf16 bits [OUT_DIM][KD2]
    const float* __restrict__ bias_part,     // [32][OUT_DIM]
    float* __restrict__ Cp,                  // [3][BATCH*OUT_DIM] partials
    float* __restrict__ C) {                 // [BATCH][OUT_DIM]
    extern __shared__ __align__(16) unsigned short lds[];  // 128 KiB dynamic

    const int tid  = threadIdx.x;
    const int bidx = blockIdx.x;
    // XCD map: bidx&7 = ch*2 + mhalf. 32 blocks/XCD: 8 m-tiles x 4 n-tiles
    // of ONE K-chunk -> per-XCD panel footprint ~11 MB.
    const int xcd   = bidx & 7;
    const int ch    = xcd >> 1;
    const int mhalf = xcd & 1;
    const int loc   = bidx >> 3;                 // 0..31
    const int m0 = ((loc >> 2) + mhalf * 8) * BM2;
    const int n0 = (loc & 3) * BN2;
    const size_t kb = (size_t)ch * KCH;

    const int lane  = tid & 63;
    const int w     = tid >> 6;
    const int wmG   = (w >> 2) * 128;   // wave m-offset within tile (0 / 128)
    const int wnG   = (w & 3) * 64;     // wave n-offset within tile
    const int row16 = lane & 15;
    const int quad  = lane >> 4;

    // LDS byte addresses of fragments (slot 0; slot 1 via offset:32768).
    const unsigned ldsb = lds_off(lds);
    unsigned aA[8], bA[4];
#pragma unroll
    for (int mf = 0; mf < 8; ++mf) {
        int r = wmG + mf * 16 + row16;
        aA[mf] = ldsb + 2u * (unsigned)(r * 64 + ((quad ^ (r & 7)) * 8));
    }
#pragma unroll
    for (int nf = 0; nf < 4; ++nf) {
        int c = wnG + nf * 16 + row16;
        bA[nf] = ldsb + 65536u + 2u * (unsigned)(c * 64 + ((quad ^ (c & 7)) * 8));
    }

    // Staging: load L covers rows [64L, 64L+64); thread t -> row rst=t>>3,
    // phys chunk s0=t&7; global source pre-swizzled: logical chunk s0^(rst&7).
    const int rst = tid >> 3;
    const int sw  = ((tid & 7) ^ (rst & 7)) * 8;
    const unsigned short* gA = A  + (size_t)(m0 + rst) * KD2 + kb + sw;
    const unsigned short* gB = Bt + (size_t)(n0 + rst) * KD2 + kb + sw;

    f32x4  acc[8][4] = {};
    bf16x8 bF[4][2];

    // Prologue: 14 loads in the exact order the wait counts assume.
    ISSUE_B(0, 0, 0); ISSUE_B(0, 0, 1); ISSUE_B(0, 0, 2); ISSUE_B(0, 0, 3);
    ISSUE_A(0, 0, 0); ISSUE_A(0, 0, 2);
    ISSUE_A(0, 0, 1); ISSUE_A(0, 0, 3);
    ISSUE_B(1, 1, 0); ISSUE_B(1, 1, 1); ISSUE_B(1, 1, 2); ISSUE_B(1, 1, 3);
    ISSUE_A(1, 1, 0); ISSUE_A(1, 1, 2);
    asm volatile("s_waitcnt vmcnt(8)" ::: "memory");
    __builtin_amdgcn_s_barrier();

#pragma unroll 1
    for (int t = 0; t < NT; t += 2) {
        TILE_BODY(t, 0)
        TILE_BODY(t + 1, 1)
    }

    // Drain dummy tail prefetches before reusing LDS.
    asm volatile("s_waitcnt vmcnt(0)" ::: "memory");
    __syncthreads();

    // ch==0 folds in the exact d=0 bias: sbias[col] = sum_g bias_part[g][col]
    float* sbf = (float*)lds;
    if (ch == 0) {
        if (tid < 256) {
            float s = 0.f;
#pragma unroll
            for (int gg = 0; gg < 32; ++gg)
                s += bias_part[(size_t)gg * OUT_DIM + n0 + tid];
            sbf[tid] = s;
        }
        __syncthreads();
    }

    // Store epilogue (R6): ch==0 -> C, ch>0 -> Cp plane ch-1. No atomics.
    float* dst = (ch == 0) ? C : (Cp + (size_t)(ch - 1) * BATCH * OUT_DIM);
    // C/D layout (m89-verified): col = lane&15, row = quad*4 + reg
#pragma unroll
    for (int mf = 0; mf < 8; ++mf) {
        const int rbase = m0 + wmG + mf * 16 + quad * 4;
#pragma unroll
        for (int nf = 0; nf < 4; ++nf) {
            const int col = n0 + wnG + nf * 16 + row16;
            const float bv = (ch == 0) ? sbf[wnG + nf * 16 + row16] : 0.f;
#pragma unroll
            for (int r = 0; r < 4; ++r)
                dst[(size_t)(rbase + r) * OUT_DIM + col] = acc[mf][nf][r] + bv;
        }
    }
}

// ---------------------------------------------------------------------------
// 2-phase 128x128 atomic GEMM — mid-workspace fallback path (R9-identical).
// ---------------------------------------------------------------------------
#define BM 128
#define BN 128
#define BK 64

__global__ __launch_bounds__(256, 4) void gemm_atomic(
    const unsigned short* __restrict__ A,
    const unsigned short* __restrict__ Bt,
    const float* __restrict__ bias_part,
    float* __restrict__ C) {                 // pre-zeroed
    __shared__ __align__(16) unsigned short lA[BM * BK];
    __shared__ __align__(16) unsigned short lB[BN * BK];
    const int tid  = threadIdx.x;
    const int bidx = blockIdx.x;
    const int ch    = (bidx & 7) >> 1;
    const int mhalf = bidx & 1;
    const int loc   = bidx >> 3;
    const int m0 = ((loc >> 3) + mhalf * 16) * BM;
    const int n0 = (loc & 7) * BN;
    const size_t kb = (size_t)ch * KCH;
    const int lane  = tid & 63;
    const int wid   = tid >> 6;
    const int wm    = (wid & 1) * 64;
    const int wn    = (wid >> 1) * 64;
    const int row16 = lane & 15;
    const int quad  = lane >> 4;
    int aOff[4], bOff[4];
#pragma unroll
    for (int mt = 0; mt < 4; ++mt) {
        int r = wm + mt * 16 + row16;
        aOff[mt] = r * BK + ((quad ^ (r & 7)) * 8);
    }
#pragma unroll
    for (int nt = 0; nt < 4; ++nt) {
        int c = wn + nt * 16 + row16;
        bOff[nt] = c * BK + ((quad ^ (c & 7)) * 8);
    }
    const int r0 = tid >> 3, s0 = tid & 7;
    const unsigned short* gA0 = A  + (size_t)(m0 + r0) * KD2 + kb + ((s0 ^ (r0 & 7)) * 8);
    const unsigned short* gB0 = Bt + (size_t)(n0 + r0) * KD2 + kb + ((s0 ^ (r0 & 7)) * 8);
    unsigned short* dA = lA + tid * 8;
    unsigned short* dB = lB + tid * 8;
    f32x4 acc[4][4] = {};
    for (int k0 = 0; k0 < KCH; k0 += BK) {
#pragma unroll
        for (int j = 0; j < 4; ++j)
            ld_lds16(gA0 + k0 + (size_t)j * 32 * KD2, dA + j * 2048);
#pragma unroll
        for (int j = 0; j < 4; ++j)
            ld_lds16(gB0 + k0 + (size_t)j * 32 * KD2, dB + j * 2048);
        __syncthreads();
#pragma unroll
        for (int kk = 0; kk < 2; ++kk) {
            const int xo = kk * 32;
            bf16x8 aF[4], bF[4];
#pragma unroll
            for (int mt = 0; mt < 4; ++mt) aF[mt] = *(const bf16x8*)(lA + (aOff[mt] ^ xo));
#pragma unroll
            for (int nt = 0; nt < 4; ++nt) bF[nt] = *(const bf16x8*)(lB + (bOff[nt] ^ xo));
#pragma unroll
            for (int mt = 0; mt < 4; ++mt)
#pragma unroll
                for (int nt = 0; nt < 4; ++nt)
                    acc[mt][nt] = __builtin_amdgcn_mfma_f32_16x16x32_bf16(
                        aF[mt], bF[nt], acc[mt][nt], 0, 0, 0);
        }
        __syncthreads();
    }
    if (ch == 0) {
        float* sbw = (float*)lA;
        if (tid < BN) {
            float s = 0.f;
#pragma unroll
            for (int g = 0; g < 32; ++g) s += bias_part[(size_t)g * OUT_DIM + n0 + tid];
            sbw[tid] = s;
        }
        __syncthreads();
    }
    const float* sb = (const float*)lA;
#pragma unroll
    for (int mt = 0; mt < 4; ++mt) {
        const int rbase = m0 + wm + mt * 16 + quad * 4;
#pragma unroll
        for (int nt = 0; nt < 4; ++nt) {
            const int col = n0 + wn + nt * 16 + row16;
            const float bv = (ch == 0) ? sb[wn + nt * 16 + row16] : 0.f;
#pragma unroll
            for (int r = 0; r < 4; ++r)
                atomicAdd(&C[(size_t)(rbase + r) * OUT_DIM + col], acc[mt][nt][r] + bv);
        }
    }
}

// ---------------------------------------------------------------------------
// Kernel 3: reduce — C += Cp1 + Cp2 + Cp3 (R6-identical). 80 MB ~ 13 us.
// ---------------------------------------------------------------------------
__global__ __launch_bounds__(256) void reduce_kernel(
    const float* __restrict__ Cp,   // [3][BATCH*OUT_DIM]
    float* __restrict__ C) {
    const size_t P = (size_t)BATCH * OUT_DIM;
    const size_t base = (size_t)blockIdx.x * 4096 + threadIdx.x * 4;
#pragma unroll
    for (int j = 0; j < 4; ++j) {
        const size_t idx = base + (size_t)j * 1024;
        f32x4 v  = *(const f32x4*)(C + idx);
        f32x4 v1 = *(const f32x4*)(Cp + idx);
        f32x4 v2 = *(const f32x4*)(Cp + P + idx);
        f32x4 v3 = *(const f32x4*)(Cp + 2 * P + idx);
        v = v + v1 + v2 + v3;
        *(f32x4*)(C + idx) = v;
    }
}

// ---------------------------------------------------------------------------
// Fallback (only if ws too small): fp32, block per batch row, basis in LDS.
// ---------------------------------------------------------------------------
__global__ __launch_bounds__(256) void fallback_kernel(
    const float* __restrict__ x, const float* __restrict__ ap,
    const float* __restrict__ qp, const float* __restrict__ coeffs,
    float* __restrict__ out) {
    __shared__ float sb[IN_DIM][NB];   // 32 KB
    const int b = blockIdx.x;
    const float a = ap[0], q = qp[0];
    for (int i = threadIdx.x; i < IN_DIM; i += 256) {
        float xt = fast_tanh(x[(size_t)b * IN_DIM + i]);
        float p0 = 1.0f, p1 = xt - a;
        sb[i][0] = p0; sb[i][1] = p1;
        float qn = q, qn1 = 1.0f;
#pragma unroll
        for (int n = 2; n < NB; ++n) {
            qn *= q; qn1 *= q;
            float p2 = (xt - (a + qn)) * p1 - a * qn1 * p0;
            sb[i][n] = p2;
            p0 = p1; p1 = p2;
        }
    }
    __syncthreads();
    float acc[4] = {0.f, 0.f, 0.f, 0.f};
    for (int i = 0; i < IN_DIM; ++i) {
        float bb[NB];
#pragma unroll
        for (int d = 0; d < NB; ++d) bb[d] = sb[i][d];
#pragma unroll
        for (int j = 0; j < 4; ++j) {
            int o = threadIdx.x + j * 256;
            const float* cf = coeffs + ((size_t)i * OUT_DIM + o) * NB;
            float s = 0.f;
#pragma unroll
            for (int d = 0; d < NB; ++d) s += bb[d] * cf[d];
            acc[j] += s;
        }
    }
#pragma unroll
    for (int j = 0; j < 4; ++j)
        out[(size_t)b * OUT_DIM + threadIdx.x + j * 256] = acc[j];
}

// ---------------------------------------------------------------------------
extern "C" void kernel_launch(void* const* d_in, const int* in_sizes, int n_in,
                              void* d_out, int out_size, void* d_ws, size_t ws_size,
                              hipStream_t stream) {
    const float* x      = (const float*)d_in[0];
    const float* a      = (const float*)d_in[1];
    const float* q      = (const float*)d_in[2];
    const float* coeffs = (const float*)d_in[3];
    float* out = (float*)d_out;

    const size_t needA = (size_t)BATCH * KD2 * sizeof(unsigned short);   // 56 MB
    const size_t needB = (size_t)OUT_DIM * KD2 * sizeof(unsigned short); // 14 MB
    const size_t needBias = 32 * (size_t)OUT_DIM * sizeof(float);        // 128 KB
    const size_t needCp = 3 * (size_t)BATCH * OUT_DIM * sizeof(float);   // 48 MB

    if (ws_size >= needA + needB + needBias + needCp) {
        // Preferred path (3 dispatches): prep -> 8-phase gemm -> reduce.
        static bool lds_attr_set = false;
        if (!lds_attr_set) {
            (void)hipFuncSetAttribute(
                reinterpret_cast<const void*>(&gemm8_store),
                hipFuncAttributeMaxDynamicSharedMemorySize, GEMM_LDS);
            lds_attr_set = true;
        }
        unsigned short* Aw = (unsigned short*)d_ws;
        unsigned short* Bt = Aw + (size_t)BATCH * KD2;
        float* bias_part = (float*)((char*)d_ws + needA + needB);
        float* Cp = (float*)((char*)d_ws + needA + needB + needBias);
        prep_kernel<<<PREP_BLOCKS, 256, 0, stream>>>(
            x, a, q, coeffs, Aw, Bt, bias_part);
        gemm8_store<<<(BATCH / BM2) * (OUT_DIM / BN2) * KSPLIT, 512, GEMM_LDS,
                      stream>>>(Aw, Bt, bias_part, Cp, out);
        reduce_kernel<<<BATCH * OUT_DIM / 4096, 256, 0, stream>>>(Cp, out);
    } else if (ws_size >= needA + needB + needBias) {
        // Atomic path (known-good ~202 us).
        unsigned short* Aw = (unsigned short*)d_ws;
        unsigned short* Bt = Aw + (size_t)BATCH * KD2;
        float* bias_part = (float*)((char*)d_ws + needA + needB);
        prep_kernel<<<PREP_BLOCKS, 256, 0, stream>>>(
            x, a, q, coeffs, Aw, Bt, bias_part);
        zero_kernel<<<ZERO_BLOCKS, 256, 0, stream>>>(out);
        gemm_atomic<<<(BATCH / BM) * (OUT_DIM / BN) * KSPLIT, 256, 0, stream>>>(
            Aw, Bt, bias_part, out);
    } else {
        fallback_kernel<<<BATCH, 256, 0, stream>>>(x, a, q, coeffs, out);
    }
}

// Round 11
// 164.535 us; speedup vs baseline: 2.2792x; 1.0221x over previous
//
#include <hip/hip_runtime.h>

#define BATCH   4096
#define IN_DIM  1024
#define OUT_DIM 1024
#define NB      8                 // DEGREE + 1
#define NBK     7                 // basis funcs in the GEMM (d=1..7; d=0 is a bias)
#define KD2     (IN_DIM * NBK)    // 7168
// Workspace K-layout (d-major): k = (d-1)*IN_DIM + i, for BOTH A and Bt.
// R5 lesson: hipLaunchCooperativeKernel is NOT graph-capturable here (hang x2).
// R7 lesson: device-scope __threadfence in a hot kernel -> L2 writeback storm.
// R6 lesson: split-K atomics cost ~28 us -> plain stores + separate reduce.
// R9 lesson: XCD = (ch, m-half) remap -> FETCH -40%.
// R10: 8-phase 256^2 + store epilogue + XCD map -> best total 168.2 us
// (FETCH 43 MB). R11: reduce micro-opt only (2048 blocks + nontemporal Cp
// loads); everything else byte-identical to R10.

typedef __bf16 bf16x8 __attribute__((ext_vector_type(8)));
typedef float  f32x4  __attribute__((ext_vector_type(4)));
typedef unsigned short us8 __attribute__((ext_vector_type(8)));
typedef unsigned short us4 __attribute__((ext_vector_type(4)));

__device__ __forceinline__ unsigned short f2bf(float f) {
    unsigned int u = __float_as_uint(f);
    u += 0x7fffu + ((u >> 16) & 1u);   // round-to-nearest-even
    return (unsigned short)(u >> 16);
}

// fast tanh: 1 - 2/(e^{2x}+1) via v_exp_f32 + v_rcp_f32; exact limits at +-inf.
__device__ __forceinline__ float fast_tanh(float x) {
    const float LOG2E_X2 = 2.8853900817779268f;   // 2*log2(e)
    float e = __builtin_amdgcn_exp2f(x * LOG2E_X2);
    return 1.0f - 2.0f * __builtin_amdgcn_rcpf(e + 1.0f);
}

__device__ __forceinline__ void ld_lds16(const unsigned short* g, unsigned short* l) {
    __builtin_amdgcn_global_load_lds(
        (const __attribute__((address_space(1))) void*)g,
        (__attribute__((address_space(3))) void*)l, 16, 0, 0);
}

// 32-bit LDS offset of a generic pointer that points into LDS.
__device__ __forceinline__ unsigned lds_off(const void* p) {
    return (unsigned)(unsigned long long)
        (const __attribute__((address_space(3))) void*)p;
}

// Inline-asm ds_read_b128: opaque to SIInsertWaitcnts so the compiler can't
// graft conservative vmcnt waits (LDS-DMA aliasing) onto the counted-vmcnt
// pipeline. Ordering is explicit: barrier -> lgkmcnt(0) -> sched_barrier(0).
template <int OFF>
__device__ __forceinline__ bf16x8 dsr128(unsigned addr) {
    f32x4 r;
    asm volatile("ds_read_b128 %0, %1 offset:%c2"
                 : "=v"(r) : "v"(addr), "i"(OFF));
    union { f32x4 f; bf16x8 h; } u; u.f = r; return u.h;
}

// ---------------------------------------------------------------------------
// Kernel 1: fused prep (basis + repack), two block-role ranges. UNCHANGED.
// ---------------------------------------------------------------------------
#define REPACK_BLOCKS 512
#define BASIS_BLOCKS  (BATCH / 2)              // 2048
#define PREP_BLOCKS   (REPACK_BLOCKS + BASIS_BLOCKS)
#define TI 32
#define TO 64
#define RSTR 232    // LDS row stride (ushorts) per o: 224 data + 8 pad

__global__ __launch_bounds__(256) void prep_kernel(
    const float* __restrict__ x, const float* __restrict__ ap,
    const float* __restrict__ qp, const float* __restrict__ coeffs,
    unsigned short* __restrict__ Aw, unsigned short* __restrict__ Bt,
    float* __restrict__ bias_part) {  // [32][OUT_DIM]
    __shared__ __align__(16) unsigned short lt[TO * RSTR + 512];  // 30.0 KB
    const int tid = threadIdx.x;

    if (blockIdx.x < REPACK_BLOCKS) {
        // ---- repack + bias partials: patch i0..i0+32 x o0..o0+64 ----
        const int bid = blockIdx.x;
        const int g  = bid & 31;
        const int i0 = g * TI;
        const int o0 = (bid >> 5) * TO;
        const int o_local = tid & 63;
        float bpart = 0.f;
#pragma unroll
        for (int pass = 0; pass < 8; ++pass) {
            const int i_local = pass * 4 + (tid >> 6);
            const float* src = coeffs +
                ((size_t)(i0 + i_local) * OUT_DIM + (o0 + o_local)) * NB;
            float4 v0 = *(const float4*)src;
            float4 v1 = *(const float4*)(src + 4);
            bpart += v0.x;                       // d = 0 -> exact fp32 bias
            unsigned short* dst = lt + o_local * RSTR + i_local;
            dst[0]   = f2bf(v0.y); dst[32]  = f2bf(v0.z); dst[64]  = f2bf(v0.w);
            dst[96]  = f2bf(v1.x); dst[128] = f2bf(v1.y); dst[160] = f2bf(v1.z);
            dst[192] = f2bf(v1.w);
        }
        float* sb = (float*)(lt + TO * RSTR);    // 256 floats
        sb[(tid >> 6) * 64 + o_local] = bpart;
        __syncthreads();
        if (tid < 64)
            bias_part[(size_t)g * OUT_DIM + o0 + tid] =
                sb[tid] + sb[64 + tid] + sb[128 + tid] + sb[192 + tid];
#pragma unroll
        for (int p = 0; p < 7; ++p) {
            const int o = tid >> 2;
            const int c = tid & 3;
            us8 v = *(const us8*)(lt + o * RSTR + p * 32 + c * 8);
            *(us8*)(Bt + (size_t)(o0 + o) * KD2 + (size_t)p * IN_DIM + i0 + c * 8) = v;
        }
        return;
    }

    // ---- basis: 2 rows/block; thread owns 8 contiguous i of one row ----
    const int bb  = blockIdx.x - REPACK_BLOCKS;
    const float a = ap[0], q = qp[0];
    const int b  = bb * 2 + (tid >> 7);
    const int i0 = (tid & 127) * 8;

    const float* xs = x + (size_t)b * IN_DIM + i0;
    float4 v0 = *(const float4*)xs;          // both loads issued before any use
    float4 v1 = *(const float4*)(xs + 4);

    float xe[8] = {v0.x, v0.y, v0.z, v0.w, v1.x, v1.y, v1.z, v1.w};
    float pm2[8], pm1[8];
    us8 ov;
#pragma unroll
    for (int e = 0; e < 8; ++e) {
        xe[e] = fast_tanh(xe[e]);
        pm2[e] = 1.0f;
        pm1[e] = xe[e] - a;
        ov[e] = f2bf(pm1[e]);
    }
    unsigned short* arow = Aw + (size_t)b * KD2 + i0;
    *(us8*)arow = ov;                         // d=1 plane
    float qn = q, qn1 = 1.0f;
#pragma unroll
    for (int n = 2; n < NB; ++n) {
        qn *= q; qn1 *= q;
#pragma unroll
        for (int e = 0; e < 8; ++e) {
            float pn = (xe[e] - (a + qn)) * pm1[e] - a * qn1 * pm2[e];
            pm2[e] = pm1[e]; pm1[e] = pn;
            ov[e] = f2bf(pn);
        }
        *(us8*)(arow + (size_t)(n - 1) * IN_DIM) = ov;   // d=n plane, 16 B
    }
}

// ---------------------------------------------------------------------------
// zero C — used ONLY by the atomic fallback path.
// ---------------------------------------------------------------------------
#define ZERO_BLOCKS   (BATCH * OUT_DIM / 4096) // 1024

__global__ __launch_bounds__(256) void zero_kernel(float* __restrict__ C) {
    float* dst = C + (size_t)blockIdx.x * 4096 + threadIdx.x * 4;
    const f32x4 zero = {0.f, 0.f, 0.f, 0.f};
#pragma unroll
    for (int j = 0; j < 4; ++j) *(f32x4*)(dst + j * 1024) = zero;
}

#define KSPLIT 4
#define KCH (KD2 / KSPLIT)   // 1792

// ---------------------------------------------------------------------------
// Kernel 2 (preferred): 256x256 8-phase counted-vmcnt GEMM, store epilogue.
// UNCHANGED from R10 (best total). Schedule audit in R10 comments.
// ---------------------------------------------------------------------------
#define BM2 256
#define BN2 256
#define BK2 64
#define NT  (KCH / BK2)      // 28 K-tiles per chunk
#define GEMM_LDS 131072

#define ISSUE_A(TT_, SL_, L_)                                                  \
    ld_lds16(gA + (size_t)(L_) * 64 * KD2 +                                    \
                 (size_t)((TT_) < NT ? (TT_) : (NT - 1)) * 64,                 \
             lds + (SL_) * 16384 + (L_) * 4096 + tid * 8)

#define ISSUE_B(TT_, SL_, L_)                                                  \
    ld_lds16(gB + (size_t)(L_) * 64 * KD2 +                                    \
                 (size_t)((TT_) < NT ? (TT_) : (NT - 1)) * 64,                 \
             lds + 32768 + (SL_) * 16384 + (L_) * 4096 + tid * 8)

#define BARRIER_A()                                                            \
    __builtin_amdgcn_s_barrier();                                              \
    asm volatile("s_waitcnt lgkmcnt(0)" ::: "memory");                         \
    __builtin_amdgcn_sched_barrier(0);

#define MFMA16(M_, A0_, A1_, A2_, A3_)                                         \
    __builtin_amdgcn_s_setprio(1);                                             \
    _Pragma("unroll") for (int nf = 0; nf < 4; ++nf) {                         \
        acc[M_][nf] = __builtin_amdgcn_mfma_f32_16x16x32_bf16(                 \
            A0_, bF[nf][0], acc[M_][nf], 0, 0, 0);                             \
        acc[M_][nf] = __builtin_amdgcn_mfma_f32_16x16x32_bf16(                 \
            A1_, bF[nf][1], acc[M_][nf], 0, 0, 0);                             \
        acc[(M_) + 1][nf] = __builtin_amdgcn_mfma_f32_16x16x32_bf16(           \
            A2_, bF[nf][0], acc[(M_) + 1][nf], 0, 0, 0);                       \
        acc[(M_) + 1][nf] = __builtin_amdgcn_mfma_f32_16x16x32_bf16(           \
            A3_, bF[nf][1], acc[(M_) + 1][nf], 0, 0, 0);                       \
    }                                                                          \
    __builtin_amdgcn_s_setprio(0);                                             \
    __builtin_amdgcn_sched_barrier(0);

#define TILE_BODY(T_, P_)                                                      \
    {                                                                          \
        constexpr int OFF = (P_) * 32768;                                      \
        { /* ---- P0 ---- */                                                   \
            bf16x8 a0 = dsr128<OFF>(aA[0]), a1 = dsr128<OFF>(aA[0] ^ 64);      \
            bf16x8 a2 = dsr128<OFF>(aA[1]), a3 = dsr128<OFF>(aA[1] ^ 64);      \
            _Pragma("unroll") for (int nf = 0; nf < 4; ++nf) {                 \
                bF[nf][0] = dsr128<OFF>(bA[nf]);                               \
                bF[nf][1] = dsr128<OFF>(bA[nf] ^ 64);                          \
            }                                                                  \
            ISSUE_A((T_) + 1, (P_) ^ 1, 1);                                    \
            ISSUE_A((T_) + 1, (P_) ^ 1, 3);                                    \
            BARRIER_A()                                                        \
            MFMA16(0, a0, a1, a2, a3)                                          \
            __builtin_amdgcn_s_barrier();                                      \
        }                                                                      \
        { /* ---- P1 ---- */                                                   \
            bf16x8 a0 = dsr128<OFF>(aA[2]), a1 = dsr128<OFF>(aA[2] ^ 64);      \
            bf16x8 a2 = dsr128<OFF>(aA[3]), a3 = dsr128<OFF>(aA[3] ^ 64);      \
            ISSUE_B((T_) + 2, (P_), 0);                                        \
            ISSUE_B((T_) + 2, (P_), 1);                                        \
            BARRIER_A()                                                        \
            MFMA16(2, a0, a1, a2, a3)                                          \
            asm volatile("s_waitcnt vmcnt(10)" ::: "memory");                  \
            __builtin_amdgcn_s_barrier();                                      \
        }                                                                      \
        { /* ---- P2 ---- */                                                   \
            bf16x8 a0 = dsr128<OFF>(aA[4]), a1 = dsr128<OFF>(aA[4] ^ 64);      \
            bf16x8 a2 = dsr128<OFF>(aA[5]), a3 = dsr128<OFF>(aA[5] ^ 64);      \
            ISSUE_B((T_) + 2, (P_), 2);                                        \
            ISSUE_B((T_) + 2, (P_), 3);                                        \
            BARRIER_A()                                                        \
            MFMA16(4, a0, a1, a2, a3)                                          \
            __builtin_amdgcn_s_barrier();                                      \
        }                                                                      \
        { /* ---- P3 ---- */                                                   \
            bf16x8 a0 = dsr128<OFF>(aA[6]), a1 = dsr128<OFF>(aA[6] ^ 64);      \
            bf16x8 a2 = dsr128<OFF>(aA[7]), a3 = dsr128<OFF>(aA[7] ^ 64);      \
            ISSUE_A((T_) + 2, (P_), 0);                                        \
            ISSUE_A((T_) + 2, (P_), 2);                                        \
            BARRIER_A()                                                        \
            MFMA16(6, a0, a1, a2, a3)                                          \
            asm volatile("s_waitcnt vmcnt(8)" ::: "memory");                   \
            __builtin_amdgcn_s_barrier();                                      \
        }                                                                      \
    }

__global__ __launch_bounds__(512, 2) void gemm8_store(
    const unsigned short* __restrict__ A,    // bf16 bits [BATCH][KD2]
    const unsigned short* __restrict__ Bt,   // bf16 bits [OUT_DIM][KD2]
    const float* __restrict__ bias_part,     // [32][OUT_DIM]
    float* __restrict__ Cp,                  // [3][BATCH*OUT_DIM] partials
    float* __restrict__ C) {                 // [BATCH][OUT_DIM]
    extern __shared__ __align__(16) unsigned short lds[];  // 128 KiB dynamic

    const int tid  = threadIdx.x;
    const int bidx = blockIdx.x;
    // XCD map: bidx&7 = ch*2 + mhalf. 32 blocks/XCD: 8 m-tiles x 4 n-tiles
    // of ONE K-chunk -> per-XCD panel footprint ~11 MB.
    const int xcd   = bidx & 7;
    const int ch    = xcd >> 1;
    const int mhalf = xcd & 1;
    const int loc   = bidx >> 3;                 // 0..31
    const int m0 = ((loc >> 2) + mhalf * 8) * BM2;
    const int n0 = (loc & 3) * BN2;
    const size_t kb = (size_t)ch * KCH;

    const int lane  = tid & 63;
    const int w     = tid >> 6;
    const int wmG   = (w >> 2) * 128;   // wave m-offset within tile (0 / 128)
    const int wnG   = (w & 3) * 64;     // wave n-offset within tile
    const int row16 = lane & 15;
    const int quad  = lane >> 4;

    // LDS byte addresses of fragments (slot 0; slot 1 via offset:32768).
    const unsigned ldsb = lds_off(lds);
    unsigned aA[8], bA[4];
#pragma unroll
    for (int mf = 0; mf < 8; ++mf) {
        int r = wmG + mf * 16 + row16;
        aA[mf] = ldsb + 2u * (unsigned)(r * 64 + ((quad ^ (r & 7)) * 8));
    }
#pragma unroll
    for (int nf = 0; nf < 4; ++nf) {
        int c = wnG + nf * 16 + row16;
        bA[nf] = ldsb + 65536u + 2u * (unsigned)(c * 64 + ((quad ^ (c & 7)) * 8));
    }

    // Staging: load L covers rows [64L, 64L+64); thread t -> row rst=t>>3,
    // phys chunk s0=t&7; global source pre-swizzled: logical chunk s0^(rst&7).
    const int rst = tid >> 3;
    const int sw  = ((tid & 7) ^ (rst & 7)) * 8;
    const unsigned short* gA = A  + (size_t)(m0 + rst) * KD2 + kb + sw;
    const unsigned short* gB = Bt + (size_t)(n0 + rst) * KD2 + kb + sw;

    f32x4  acc[8][4] = {};
    bf16x8 bF[4][2];

    // Prologue: 14 loads in the exact order the wait counts assume.
    ISSUE_B(0, 0, 0); ISSUE_B(0, 0, 1); ISSUE_B(0, 0, 2); ISSUE_B(0, 0, 3);
    ISSUE_A(0, 0, 0); ISSUE_A(0, 0, 2);
    ISSUE_A(0, 0, 1); ISSUE_A(0, 0, 3);
    ISSUE_B(1, 1, 0); ISSUE_B(1, 1, 1); ISSUE_B(1, 1, 2); ISSUE_B(1, 1, 3);
    ISSUE_A(1, 1, 0); ISSUE_A(1, 1, 2);
    asm volatile("s_waitcnt vmcnt(8)" ::: "memory");
    __builtin_amdgcn_s_barrier();

#pragma unroll 1
    for (int t = 0; t < NT; t += 2) {
        TILE_BODY(t, 0)
        TILE_BODY(t + 1, 1)
    }

    // Drain dummy tail prefetches before reusing LDS.
    asm volatile("s_waitcnt vmcnt(0)" ::: "memory");
    __syncthreads();

    // ch==0 folds in the exact d=0 bias: sbias[col] = sum_g bias_part[g][col]
    float* sbf = (float*)lds;
    if (ch == 0) {
        if (tid < 256) {
            float s = 0.f;
#pragma unroll
            for (int gg = 0; gg < 32; ++gg)
                s += bias_part[(size_t)gg * OUT_DIM + n0 + tid];
            sbf[tid] = s;
        }
        __syncthreads();
    }

    // Store epilogue (R6): ch==0 -> C, ch>0 -> Cp plane ch-1. No atomics.
    float* dst = (ch == 0) ? C : (Cp + (size_t)(ch - 1) * BATCH * OUT_DIM);
    // C/D layout (m89-verified): col = lane&15, row = quad*4 + reg
#pragma unroll
    for (int mf = 0; mf < 8; ++mf) {
        const int rbase = m0 + wmG + mf * 16 + quad * 4;
#pragma unroll
        for (int nf = 0; nf < 4; ++nf) {
            const int col = n0 + wnG + nf * 16 + row16;
            const float bv = (ch == 0) ? sbf[wnG + nf * 16 + row16] : 0.f;
#pragma unroll
            for (int r = 0; r < 4; ++r)
                dst[(size_t)(rbase + r) * OUT_DIM + col] = acc[mf][nf][r] + bv;
        }
    }
}

// ---------------------------------------------------------------------------
// 2-phase 128x128 atomic GEMM — mid-workspace fallback path (unchanged).
// ---------------------------------------------------------------------------
#define BM 128
#define BN 128
#define BK 64

__global__ __launch_bounds__(256, 4) void gemm_atomic(
    const unsigned short* __restrict__ A,
    const unsigned short* __restrict__ Bt,
    const float* __restrict__ bias_part,
    float* __restrict__ C) {                 // pre-zeroed
    __shared__ __align__(16) unsigned short lA[BM * BK];
    __shared__ __align__(16) unsigned short lB[BN * BK];
    const int tid  = threadIdx.x;
    const int bidx = blockIdx.x;
    const int ch    = (bidx & 7) >> 1;
    const int mhalf = bidx & 1;
    const int loc   = bidx >> 3;
    const int m0 = ((loc >> 3) + mhalf * 16) * BM;
    const int n0 = (loc & 7) * BN;
    const size_t kb = (size_t)ch * KCH;
    const int lane  = tid & 63;
    const int wid   = tid >> 6;
    const int wm    = (wid & 1) * 64;
    const int wn    = (wid >> 1) * 64;
    const int row16 = lane & 15;
    const int quad  = lane >> 4;
    int aOff[4], bOff[4];
#pragma unroll
    for (int mt = 0; mt < 4; ++mt) {
        int r = wm + mt * 16 + row16;
        aOff[mt] = r * BK + ((quad ^ (r & 7)) * 8);
    }
#pragma unroll
    for (int nt = 0; nt < 4; ++nt) {
        int c = wn + nt * 16 + row16;
        bOff[nt] = c * BK + ((quad ^ (c & 7)) * 8);
    }
    const int r0 = tid >> 3, s0 = tid & 7;
    const unsigned short* gA0 = A  + (size_t)(m0 + r0) * KD2 + kb + ((s0 ^ (r0 & 7)) * 8);
    const unsigned short* gB0 = Bt + (size_t)(n0 + r0) * KD2 + kb + ((s0 ^ (r0 & 7)) * 8);
    unsigned short* dA = lA + tid * 8;
    unsigned short* dB = lB + tid * 8;
    f32x4 acc[4][4] = {};
    for (int k0 = 0; k0 < KCH; k0 += BK) {
#pragma unroll
        for (int j = 0; j < 4; ++j)
            ld_lds16(gA0 + k0 + (size_t)j * 32 * KD2, dA + j * 2048);
#pragma unroll
        for (int j = 0; j < 4; ++j)
            ld_lds16(gB0 + k0 + (size_t)j * 32 * KD2, dB + j * 2048);
        __syncthreads();
#pragma unroll
        for (int kk = 0; kk < 2; ++kk) {
            const int xo = kk * 32;
            bf16x8 aF[4], bF[4];
#pragma unroll
            for (int mt = 0; mt < 4; ++mt) aF[mt] = *(const bf16x8*)(lA + (aOff[mt] ^ xo));
#pragma unroll
            for (int nt = 0; nt < 4; ++nt) bF[nt] = *(const bf16x8*)(lB + (bOff[nt] ^ xo));
#pragma unroll
            for (int mt = 0; mt < 4; ++mt)
#pragma unroll
                for (int nt = 0; nt < 4; ++nt)
                    acc[mt][nt] = __builtin_amdgcn_mfma_f32_16x16x32_bf16(
                        aF[mt], bF[nt], acc[mt][nt], 0, 0, 0);
        }
        __syncthreads();
    }
    if (ch == 0) {
        float* sbw = (float*)lA;
        if (tid < BN) {
            float s = 0.f;
#pragma unroll
            for (int g = 0; g < 32; ++g) s += bias_part[(size_t)g * OUT_DIM + n0 + tid];
            sbw[tid] = s;
        }
        __syncthreads();
    }
    const float* sb = (const float*)lA;
#pragma unroll
    for (int mt = 0; mt < 4; ++mt) {
        const int rbase = m0 + wm + mt * 16 + quad * 4;
#pragma unroll
        for (int nt = 0; nt < 4; ++nt) {
            const int col = n0 + wn + nt * 16 + row16;
            const float bv = (ch == 0) ? sb[wn + nt * 16 + row16] : 0.f;
#pragma unroll
            for (int r = 0; r < 4; ++r)
                atomicAdd(&C[(size_t)(rbase + r) * OUT_DIM + col], acc[mt][nt][r] + bv);
        }
    }
}

// ---------------------------------------------------------------------------
// Kernel 3: reduce — C += Cp1 + Cp2 + Cp3. R11: 2048 blocks x 2048 floats
// (more waves in flight for a short streaming kernel) + nontemporal loads on
// the single-use Cp planes. Same per-element addition order -> bit-identical.
// ---------------------------------------------------------------------------
#define RED_BLOCKS (BATCH * OUT_DIM / 2048)   // 2048

__global__ __launch_bounds__(256) void reduce_kernel(
    const float* __restrict__ Cp,   // [3][BATCH*OUT_DIM]
    float* __restrict__ C) {
    const size_t P = (size_t)BATCH * OUT_DIM;
    const size_t base = (size_t)blockIdx.x * 2048 + threadIdx.x * 4;
#pragma unroll
    for (int j = 0; j < 2; ++j) {
        const size_t idx = base + (size_t)j * 1024;
        f32x4 v  = *(const f32x4*)(C + idx);
        f32x4 v1 = __builtin_nontemporal_load((const f32x4*)(Cp + idx));
        f32x4 v2 = __builtin_nontemporal_load((const f32x4*)(Cp + P + idx));
        f32x4 v3 = __builtin_nontemporal_load((const f32x4*)(Cp + 2 * P + idx));
        v = v + v1 + v2 + v3;
        *(f32x4*)(C + idx) = v;
    }
}

// ---------------------------------------------------------------------------
// Fallback (only if ws too small): fp32, block per batch row, basis in LDS.
// ---------------------------------------------------------------------------
__global__ __launch_bounds__(256) void fallback_kernel(
    const float* __restrict__ x, const float* __restrict__ ap,
    const float* __restrict__ qp, const float* __restrict__ coeffs,
    float* __restrict__ out) {
    __shared__ float sb[IN_DIM][NB];   // 32 KB
    const int b = blockIdx.x;
    const float a = ap[0], q = qp[0];
    for (int i = threadIdx.x; i < IN_DIM; i += 256) {
        float xt = fast_tanh(x[(size_t)b * IN_DIM + i]);
        float p0 = 1.0f, p1 = xt - a;
        sb[i][0] = p0; sb[i][1] = p1;
        float qn = q, qn1 = 1.0f;
#pragma unroll
        for (int n = 2; n < NB; ++n) {
            qn *= q; qn1 *= q;
            float p2 = (xt - (a + qn)) * p1 - a * qn1 * p0;
            sb[i][n] = p2;
            p0 = p1; p1 = p2;
        }
    }
    __syncthreads();
    float acc[4] = {0.f, 0.f, 0.f, 0.f};
    for (int i = 0; i < IN_DIM; ++i) {
        float bb[NB];
#pragma unroll
        for (int d = 0; d < NB; ++d) bb[d] = sb[i][d];
#pragma unroll
        for (int j = 0; j < 4; ++j) {
            int o = threadIdx.x + j * 256;
            const float* cf = coeffs + ((size_t)i * OUT_DIM + o) * NB;
            float s = 0.f;
#pragma unroll
            for (int d = 0; d < NB; ++d) s += bb[d] * cf[d];
            acc[j] += s;
        }
    }
#pragma unroll
    for (int j = 0; j < 4; ++j)
        out[(size_t)b * OUT_DIM + threadIdx.x + j * 256] = acc[j];
}

// ---------------------------------------------------------------------------
extern "C" void kernel_launch(void* const* d_in, const int* in_sizes, int n_in,
                              void* d_out, int out_size, void* d_ws, size_t ws_size,
                              hipStream_t stream) {
    const float* x      = (const float*)d_in[0];
    const float* a      = (const float*)d_in[1];
    const float* q      = (const float*)d_in[2];
    const float* coeffs = (const float*)d_in[3];
    float* out = (float*)d_out;

    const size_t needA = (size_t)BATCH * KD2 * sizeof(unsigned short);   // 56 MB
    const size_t needB = (size_t)OUT_DIM * KD2 * sizeof(unsigned short); // 14 MB
    const size_t needBias = 32 * (size_t)OUT_DIM * sizeof(float);        // 128 KB
    const size_t needCp = 3 * (size_t)BATCH * OUT_DIM * sizeof(float);   // 48 MB

    if (ws_size >= needA + needB + needBias + needCp) {
        // Preferred path (3 dispatches): prep -> 8-phase gemm -> reduce.
        static bool lds_attr_set = false;
        if (!lds_attr_set) {
            (void)hipFuncSetAttribute(
                reinterpret_cast<const void*>(&gemm8_store),
                hipFuncAttributeMaxDynamicSharedMemorySize, GEMM_LDS);
            lds_attr_set = true;
        }
        unsigned short* Aw = (unsigned short*)d_ws;
        unsigned short* Bt = Aw + (size_t)BATCH * KD2;
        float* bias_part = (float*)((char*)d_ws + needA + needB);
        float* Cp = (float*)((char*)d_ws + needA + needB + needBias);
        prep_kernel<<<PREP_BLOCKS, 256, 0, stream>>>(
            x, a, q, coeffs, Aw, Bt, bias_part);
        gemm8_store<<<(BATCH / BM2) * (OUT_DIM / BN2) * KSPLIT, 512, GEMM_LDS,
                      stream>>>(Aw, Bt, bias_part, Cp, out);
        reduce_kernel<<<RED_BLOCKS, 256, 0, stream>>>(Cp, out);
    } else if (ws_size >= needA + needB + needBias) {
        // Atomic path (known-good ~202 us).
        unsigned short* Aw = (unsigned short*)d_ws;
        unsigned short* Bt = Aw + (size_t)BATCH * KD2;
        float* bias_part = (float*)((char*)d_ws + needA + needB);
        prep_kernel<<<PREP_BLOCKS, 256, 0, stream>>>(
            x, a, q, coeffs, Aw, Bt, bias_part);
        zero_kernel<<<ZERO_BLOCKS, 256, 0, stream>>>(out);
        gemm_atomic<<<(BATCH / BM) * (OUT_DIM / BN) * KSPLIT, 256, 0, stream>>>(
            Aw, Bt, bias_part, out);
    } else {
        fallback_kernel<<<BATCH, 256, 0, stream>>>(x, a, q, coeffs, out);
    }
}